// Round 2
// baseline (2136.680 us; speedup 1.0000x reference)
//
#include <hip/hip_runtime.h>

// ChunkedLSAttention on MI355X (gfx950).
// B=4, L=2048, D=1024, H=16, DH=64, W=128, CS=32, NCC=NCB=64, NC=128, NQ=64.
// ALL inputs/outputs are float32 (reference dtype). bf16 only for MFMA operands
// and attention K/V LDS tiles (f32 accumulate everywhere).
// Mask input (d_in[20]) is deterministic: masked iff ci-64 >= qc -> inline.
// rel_shift reduces (for unmasked entries) to pos_c index 64 + ci - qc.

typedef unsigned short u16;
typedef __attribute__((ext_vector_type(8))) short short8;
typedef __attribute__((ext_vector_type(4))) float f32x4;

#define NEGINF -1e30f

__device__ __forceinline__ float bf2f(u16 u) {
    union { unsigned int i; float f; } v; v.i = ((unsigned int)u) << 16; return v.f;
}
__device__ __forceinline__ u16 f2bf(float f) {
    union { float fl; unsigned int i; } v; v.fl = f;
    unsigned int x = v.i;
    return (u16)((x + 0x7fffu + ((x >> 16) & 1u)) >> 16);   // RNE
}

// ---------------------------------------------------------------------------
// GEMM: C(f32, MxN) = A(f32, MxK) @ B(f32, KxN) * scale + bias, bf16 MFMA.
// Block 256 = 4 waves, tile 64x64, K-chunk 32, mfma_f32_16x16x32_bf16.
// A frag: A[m=lane&15][k=quad*8+j]; B frag: B[k=quad*8+j][n=lane&15] (Bs transposed);
// D: col=lane&15, row=quad*4+r.  grid=(M/64, N/64, nbatch).
// ---------------------------------------------------------------------------
__global__ __launch_bounds__(256) void gemm_f32(
    const float* __restrict__ A, long a_bstride,
    const float* __restrict__ Bm,
    float* __restrict__ C, long c_bstride,
    int N, int K,
    const float* __restrict__ bias, float scale)
{
    const int tid = threadIdx.x;
    const int bm = blockIdx.x, bn = blockIdx.y, bz = blockIdx.z;
    A += (long)bz * a_bstride;
    C += (long)bz * c_bstride;

    __shared__ __align__(16) u16 As[64][40];   // [m][k], pad 32->40
    __shared__ __align__(16) u16 Bs[64][40];   // [n][k] (transposed)

    const int lane = tid & 63;
    const int wv = tid >> 6;
    const int wm = (wv & 1) * 32;
    const int wn = (wv >> 1) * 32;
    const int l15 = lane & 15;
    const int quad = lane >> 4;

    f32x4 acc00 = {0.f,0.f,0.f,0.f}, acc01 = {0.f,0.f,0.f,0.f};
    f32x4 acc10 = {0.f,0.f,0.f,0.f}, acc11 = {0.f,0.f,0.f,0.f};

    const int row_a = tid >> 2, col_a = (tid & 3) * 8;   // 64 rows x 32 k
    const int row_b = tid >> 3, col_b = (tid & 7) * 8;   // 32 k x 64 n
    const float* a_src = A + (long)(bm * 64 + row_a) * K + col_a;
    const float* b_src = Bm + (long)row_b * N + bn * 64 + col_b;

    for (int k0 = 0; k0 < K; k0 += 32) {
        float4 av0 = ((const float4*)a_src)[0];
        float4 av1 = ((const float4*)a_src)[1];
        a_src += 32;
        float4 bv0 = ((const float4*)b_src)[0];
        float4 bv1 = ((const float4*)b_src)[1];
        b_src += 32 * (long)N;
        __syncthreads();
        u16* ap = &As[row_a][col_a];
        ap[0] = f2bf(av0.x); ap[1] = f2bf(av0.y); ap[2] = f2bf(av0.z); ap[3] = f2bf(av0.w);
        ap[4] = f2bf(av1.x); ap[5] = f2bf(av1.y); ap[6] = f2bf(av1.z); ap[7] = f2bf(av1.w);
        Bs[col_b + 0][row_b] = f2bf(bv0.x); Bs[col_b + 1][row_b] = f2bf(bv0.y);
        Bs[col_b + 2][row_b] = f2bf(bv0.z); Bs[col_b + 3][row_b] = f2bf(bv0.w);
        Bs[col_b + 4][row_b] = f2bf(bv1.x); Bs[col_b + 5][row_b] = f2bf(bv1.y);
        Bs[col_b + 6][row_b] = f2bf(bv1.z); Bs[col_b + 7][row_b] = f2bf(bv1.w);
        __syncthreads();

        short8 a0 = *(const short8*)&As[wm + l15][quad * 8];
        short8 a1 = *(const short8*)&As[wm + 16 + l15][quad * 8];
        short8 b0 = *(const short8*)&Bs[wn + l15][quad * 8];
        short8 b1 = *(const short8*)&Bs[wn + 16 + l15][quad * 8];
        acc00 = __builtin_amdgcn_mfma_f32_16x16x32_bf16(a0, b0, acc00, 0, 0, 0);
        acc01 = __builtin_amdgcn_mfma_f32_16x16x32_bf16(a0, b1, acc01, 0, 0, 0);
        acc10 = __builtin_amdgcn_mfma_f32_16x16x32_bf16(a1, b0, acc10, 0, 0, 0);
        acc11 = __builtin_amdgcn_mfma_f32_16x16x32_bf16(a1, b1, acc11, 0, 0, 0);
    }

    f32x4 accs[2][2] = {{acc00, acc01}, {acc10, acc11}};
    #pragma unroll
    for (int i = 0; i < 2; ++i) {
        #pragma unroll
        for (int j = 0; j < 2; ++j) {
            int col = bn * 64 + wn + j * 16 + l15;
            float bsv = bias ? bias[col] : 0.f;
            #pragma unroll
            for (int r = 0; r < 4; ++r) {
                int row = bm * 64 + wm + i * 16 + quad * 4 + r;
                C[(long)row * N + col] = accs[i][j][r] * scale + bsv;
            }
        }
    }
}

// ---------------------------------------------------------------------------
// Per-chunk head scores (softmax over 32 rows of chunk, per head) and optional
// compress of src.  grid=(nchunk, B), block 256.
// ---------------------------------------------------------------------------
__global__ __launch_bounds__(256) void scores_compress(
    const float* __restrict__ src, long src_bstride,
    const float* __restrict__ Wd, const float* __restrict__ bd,
    float* __restrict__ out_comp, long comp_bstride,
    float* __restrict__ out_sc, long sc_bstride)
{
    const int c = blockIdx.x;
    const int b = blockIdx.y;
    const int tid = threadIdx.x;

    __shared__ __align__(16) u16 srcs[32][1032];   // bf16 stage, pad kills conflicts
    __shared__ float s_sm[32][16];

    const float* sb = src + (long)b * src_bstride + (long)c * 32 * 1024;
    for (int e = tid; e < 8192; e += 256) {
        int flat = e * 4;
        int row = flat >> 10, col = flat & 1023;
        float4 v = *(const float4*)(sb + (long)row * 1024 + col);
        u16* dp = &srcs[row][col];
        dp[0] = f2bf(v.x); dp[1] = f2bf(v.y); dp[2] = f2bf(v.z); dp[3] = f2bf(v.w);
    }
    __syncthreads();

    {
        int i = tid >> 3;
        int hd0 = (tid & 7) * 2;
        float acc0 = bd[hd0], acc1 = bd[hd0 + 1];
        for (int d = 0; d < 1024; ++d) {
            float xv = bf2f(srcs[i][d]);
            float2 wp = *(const float2*)(Wd + d * 16 + hd0);
            acc0 += xv * wp.x;
            acc1 += xv * wp.y;
        }
        s_sm[i][hd0] = acc0;
        s_sm[i][hd0 + 1] = acc1;
    }
    __syncthreads();

    if (tid < 16) {
        int hd = tid;
        float m = NEGINF;
        for (int i = 0; i < 32; ++i) m = fmaxf(m, s_sm[i][hd]);
        float s = 0.f;
        for (int i = 0; i < 32; ++i) s += __expf(s_sm[i][hd] - m);
        float inv = 1.f / s;
        for (int i = 0; i < 32; ++i) s_sm[i][hd] = __expf(s_sm[i][hd] - m) * inv;
    }
    __syncthreads();

    if (out_sc) {
        for (int idx = tid; idx < 512; idx += 256) {
            int hd = idx >> 5, i = idx & 31;
            out_sc[(long)b * sc_bstride + ((long)hd * 64 + c) * 32 + i] = s_sm[i][hd];
        }
    }
    if (out_comp) {
        #pragma unroll
        for (int p = 0; p < 4; ++p) {
            int j = tid + p * 256;
            int hd = j >> 6;
            float acc = 0.f;
            for (int i = 0; i < 32; ++i) acc += s_sm[i][hd] * bf2f(srcs[i][j]);
            out_comp[(long)b * comp_bstride + (long)c * 1024 + j] = acc;
        }
    }
}

// ---------------------------------------------------------------------------
// Compress already-projected k_bp/v_bp with current-block scores, then LN ->
// rows 64..127 of k_comp/v_comp.  grid=(64, B), block 256.
// ---------------------------------------------------------------------------
__global__ __launch_bounds__(256) void compress_kv_ln(
    const float* __restrict__ kbp, const float* __restrict__ vbp,
    const float* __restrict__ sc,                     // (B,16,64,32)
    const float* __restrict__ g, const float* __restrict__ be,
    float* __restrict__ k_comp, float* __restrict__ v_comp)
{
    const int c = blockIdx.x, b = blockIdx.y;
    const int tid = threadIdx.x;
    const int lane = tid & 63, wv = tid >> 6;

    __shared__ float scw[16][32];
    __shared__ float red[4][4];

    for (int idx = tid; idx < 512; idx += 256) {
        int hd = idx >> 5, i = idx & 31;
        scw[hd][i] = sc[((long)(b * 16 + hd) * 64 + c) * 32 + i];
    }
    __syncthreads();

    float xk[4], xv[4];
    #pragma unroll
    for (int p = 0; p < 4; ++p) {
        int j = tid + p * 256;
        int hd = j >> 6;
        float ak = 0.f, av = 0.f;
        for (int i = 0; i < 32; ++i) {
            float w = scw[hd][i];
            long off = ((long)b * 2048 + c * 32 + i) * 1024 + j;
            ak += w * kbp[off];
            av += w * vbp[off];
        }
        xk[p] = ak; xv[p] = av;
    }
    float sk = 0.f, qk = 0.f, sv = 0.f, qv = 0.f;
    #pragma unroll
    for (int p = 0; p < 4; ++p) { sk += xk[p]; qk += xk[p]*xk[p]; sv += xv[p]; qv += xv[p]*xv[p]; }
    for (int off = 32; off; off >>= 1) {
        sk += __shfl_xor(sk, off); qk += __shfl_xor(qk, off);
        sv += __shfl_xor(sv, off); qv += __shfl_xor(qv, off);
    }
    if (lane == 0) { red[0][wv] = sk; red[1][wv] = qk; red[2][wv] = sv; red[3][wv] = qv; }
    __syncthreads();
    sk = red[0][0] + red[0][1] + red[0][2] + red[0][3];
    qk = red[1][0] + red[1][1] + red[1][2] + red[1][3];
    sv = red[2][0] + red[2][1] + red[2][2] + red[2][3];
    qv = red[3][0] + red[3][1] + red[3][2] + red[3][3];
    const float inv_n = 1.f / 1024.f;
    float mk = sk * inv_n, mv = sv * inv_n;
    float ik = rsqrtf(fmaxf(qk * inv_n - mk * mk, 0.f) + 1e-5f);
    float iv = rsqrtf(fmaxf(qv * inv_n - mv * mv, 0.f) + 1e-5f);
    #pragma unroll
    for (int p = 0; p < 4; ++p) {
        int j = tid + p * 256;
        float gj = g[j], bj = be[j];
        long doff = ((long)b * 128 + 64 + c) * 1024 + j;
        k_comp[doff] = (xk[p] - mk) * ik * gj + bj;
        v_comp[doff] = (xv[p] - mv) * iv * gj + bj;
    }
}

// ---------------------------------------------------------------------------
// Row LayerNorm (D=1024): dst[b, off+r, :] = LN(src[b, r, :]) * g + be
// grid.x = B * rows_per_batch, block 256.
// ---------------------------------------------------------------------------
__global__ __launch_bounds__(256) void ln_rows(
    const float* __restrict__ src, long src_bstride,
    float* __restrict__ dst, long dst_bstride, long dst_row_off,
    int rows_per_batch,
    const float* __restrict__ g, const float* __restrict__ be)
{
    const int gr = blockIdx.x;
    const int b = gr / rows_per_batch, r = gr % rows_per_batch;
    const float* s = src + (long)b * src_bstride + (long)r * 1024;
    float* dp = dst + (long)b * dst_bstride + (dst_row_off + r) * 1024;
    const int tid = threadIdx.x;
    const int lane = tid & 63, wv = tid >> 6;

    __shared__ float red[2][4];
    float x[4];
    float sm = 0.f, sq = 0.f;
    #pragma unroll
    for (int p = 0; p < 4; ++p) {
        x[p] = s[tid + p * 256];
        sm += x[p]; sq += x[p] * x[p];
    }
    for (int off = 32; off; off >>= 1) { sm += __shfl_xor(sm, off); sq += __shfl_xor(sq, off); }
    if (lane == 0) { red[0][wv] = sm; red[1][wv] = sq; }
    __syncthreads();
    sm = red[0][0] + red[0][1] + red[0][2] + red[0][3];
    sq = red[1][0] + red[1][1] + red[1][2] + red[1][3];
    float m = sm * (1.f / 1024.f);
    float inv = rsqrtf(fmaxf(sq * (1.f / 1024.f) - m * m, 0.f) + 1e-5f);
    #pragma unroll
    for (int p = 0; p < 4; ++p) {
        int j = tid + p * 256;
        dp[j] = (x[p] - m) * inv * g[j] + be[j];
    }
}

// ---------------------------------------------------------------------------
// Per-row mean/rstd (D=1024) -> dst[b, off+r] = (mean, rstd). block 256.
// ---------------------------------------------------------------------------
__global__ __launch_bounds__(256) void row_stats(
    const float* __restrict__ src, long src_bstride,
    float2* __restrict__ dst, long dst_bstride, long dst_row_off,
    int rows_per_batch)
{
    const int gr = blockIdx.x;
    const int b = gr / rows_per_batch, r = gr % rows_per_batch;
    const float* s = src + (long)b * src_bstride + (long)r * 1024;
    const int tid = threadIdx.x;
    const int lane = tid & 63, wv = tid >> 6;

    __shared__ float red[2][4];
    float sm = 0.f, sq = 0.f;
    #pragma unroll
    for (int p = 0; p < 4; ++p) {
        float x = s[tid + p * 256];
        sm += x; sq += x * x;
    }
    for (int off = 32; off; off >>= 1) { sm += __shfl_xor(sm, off); sq += __shfl_xor(sq, off); }
    if (lane == 0) { red[0][wv] = sm; red[1][wv] = sq; }
    __syncthreads();
    if (tid == 0) {
        sm = red[0][0] + red[0][1] + red[0][2] + red[0][3];
        sq = red[1][0] + red[1][1] + red[1][2] + red[1][3];
        float m = sm * (1.f / 1024.f);
        float inv = rsqrtf(fmaxf(sq * (1.f / 1024.f) - m * m, 0.f) + 1e-5f);
        dst[(long)b * dst_bstride + dst_row_off + r] = make_float2(m, inv);
    }
}

// ---------------------------------------------------------------------------
// Fused attention: one block per (query-chunk qc, head h, batch b).
// 256 logits per query (128 compressed + 128 windowed), fp32 softmax, PV.
// Window K/V LayerNorm applied on the fly from row_stats.
// ---------------------------------------------------------------------------
__global__ __launch_bounds__(256) void attention(
    const float* __restrict__ q_ws,     // (B,2048,1024), already /8
    const float* __restrict__ k_comp,   // (B,128,1024)
    const float* __restrict__ v_comp,
    const float* __restrict__ kcw,      // (B,128,1024) raw cache-overlap proj
    const float* __restrict__ vcw,
    const float* __restrict__ kbp,      // (B,2048,1024) raw current proj
    const float* __restrict__ vbp,
    const float2* __restrict__ st_kw,   // (B,2176) window-K LN stats
    const float2* __restrict__ st_vw,
    const float* __restrict__ g_w, const float* __restrict__ b_w,
    const float* __restrict__ pos_c,    // (128,1024)
    const float* __restrict__ pos_t,    // (128,1024)
    const float* __restrict__ r_w,      // (16,64)
    const float* __restrict__ r_r,      // (16,64)
    float* __restrict__ attn_out)       // (B,2048,1024)
{
    const int qc = blockIdx.x, h = blockIdx.y, b = blockIdx.z;
    const int l0 = qc * 32;
    const int tid = threadIdx.x;
    const int lane = tid & 63, wv = tid >> 6;

    __shared__ float  qs [32][64];    // q
    __shared__ float  qs2[32][64];    // q + r_w_bias
    __shared__ u16    kcs[128][66];   // bf16, pad 64->66
    __shared__ u16    vcs[128][66];
    __shared__ u16    kws[160][66];
    __shared__ u16    vws[160][66];
    __shared__ float  probs[32][256];
    __shared__ float  redmax[4][32];
    __shared__ float  redsum[4][32];

    // ---- stage ----
    for (int e = tid; e < 2048; e += 256) {
        int r = e >> 6, d = e & 63;
        float qv = q_ws[((long)b * 2048 + l0 + r) * 1024 + h * 64 + d];
        qs[r][d] = qv;
        qs2[r][d] = qv + r_w[h * 64 + d];
    }
    for (int e = tid; e < 8192; e += 256) {
        int ci = e >> 6, d = e & 63;
        long off = ((long)b * 128 + ci) * 1024 + h * 64 + d;
        kcs[ci][d] = f2bf(k_comp[off]);
        vcs[ci][d] = f2bf(v_comp[off]);
    }
    for (int e = tid; e < 159 * 64; e += 256) {
        int j = e >> 6, d = e & 63;
        int t = l0 + 1 + j;                 // concat row in [1, 2176)
        float gwv = g_w[h * 64 + d], bwv = b_w[h * 64 + d];
        float2 sk = st_kw[(long)b * 2176 + t];
        float2 sv = st_vw[(long)b * 2176 + t];
        float xk, xv;
        if (t < 128) {
            long o = ((long)b * 128 + t) * 1024 + h * 64 + d;
            xk = kcw[o]; xv = vcw[o];
        } else {
            long o = ((long)b * 2048 + (t - 128)) * 1024 + h * 64 + d;
            xk = kbp[o]; xv = vbp[o];
        }
        kws[j][d] = f2bf((xk - sk.x) * sk.y * gwv + bwv);
        vws[j][d] = f2bf((xv - sv.x) * sv.y * gwv + bwv);
    }
    __syncthreads();

    // ---- logits (thread = key slot) ----
    if (tid < 128) {                       // waves 0,1: compressed keys
        int ci = tid;
        if (ci >= 64 + qc) {               // causal mask on current-block chunks
            for (int r = 0; r < 32; ++r) probs[r][tid] = NEGINF;
        } else {
            int p = 64 + ci - qc;          // rel_shift pos index
            float kp[64];
            #pragma unroll
            for (int d = 0; d < 64; ++d)
                kp[d] = bf2f(kcs[ci][d]) + pos_c[(long)p * 1024 + h * 64 + d];
            for (int r = 0; r < 32; ++r) {
                float acc = 0.f;
                #pragma unroll
                for (int d = 0; d < 64; ++d) acc += qs[r][d] * kp[d];
                probs[r][tid] = acc;
            }
        }
    } else {                               // waves 2,3: windowed keys
        int w = tid - 128;
        float pt[64];
        #pragma unroll
        for (int d = 0; d < 64; ++d) pt[d] = pos_t[(long)w * 1024 + h * 64 + d];
        float c0 = 0.f;
        #pragma unroll
        for (int d = 0; d < 64; ++d) c0 += r_r[h * 64 + d] * pt[d];
        for (int r = 0; r < 32; ++r) {
            float a1 = 0.f, a2 = 0.f;
            #pragma unroll
            for (int d = 0; d < 64; ++d) {
                a1 += qs2[r][d] * bf2f(kws[r + w][d]);   // (q+r_w) . k_win[l+1+w]
                a2 += qs[r][d] * pt[d];                  // q . pos_t[w]
            }
            probs[r][tid] = a1 + a2 + c0;                // + r_r . pos_t[w]
        }
    }
    __syncthreads();

    // ---- softmax over 256 per query row (fp32) ----
    for (int r = 0; r < 32; ++r) {
        float v = probs[r][tid];
        for (int off = 32; off; off >>= 1) v = fmaxf(v, __shfl_xor(v, off));
        if (lane == 0) redmax[wv][r] = v;
    }
    __syncthreads();
    for (int r = 0; r < 32; ++r) {
        float M = fmaxf(fmaxf(redmax[0][r], redmax[1][r]), fmaxf(redmax[2][r], redmax[3][r]));
        float e = __expf(probs[r][tid] - M);
        probs[r][tid] = e;
        float s = e;
        for (int off = 32; off; off >>= 1) s += __shfl_xor(s, off);
        if (lane == 0) redsum[wv][r] = s;
    }
    __syncthreads();
    for (int r = 0; r < 32; ++r) {
        float S = redsum[0][r] + redsum[1][r] + redsum[2][r] + redsum[3][r];
        probs[r][tid] = probs[r][tid] / S;
    }
    __syncthreads();

    // ---- PV: thread = (query group, dim) ----
    const int d = tid & 63, rg = tid >> 6;
    for (int rr = 0; rr < 8; ++rr) {
        int r = rg + rr * 4;
        float acc = 0.f;
        for (int k = 0; k < 128; ++k) acc += probs[r][k] * bf2f(vcs[k][d]);
        for (int w = 0; w < 128; ++w) acc += probs[r][128 + w] * bf2f(vws[r + w][d]);
        attn_out[((long)b * 2048 + l0 + r) * 1024 + h * 64 + d] = acc;
    }
}

// ---------------------------------------------------------------------------
extern "C" void kernel_launch(void* const* d_in, const int* in_sizes, int n_in,
                              void* d_out, int out_size, void* d_ws, size_t ws_size,
                              hipStream_t stream)
{
    (void)in_sizes; (void)n_in; (void)out_size; (void)ws_size;

    const float* h       = (const float*)d_in[0];
    const float* h_cache = (const float*)d_in[1];
    const float* key_pe  = (const float*)d_in[2];
    const float* pos_w   = (const float*)d_in[3];
    const float* Wq      = (const float*)d_in[4];
    const float* Wk      = (const float*)d_in[5];
    const float* Wv      = (const float*)d_in[6];
    const float* Wo      = (const float*)d_in[7];
    const float* Wd      = (const float*)d_in[8];
    const float* bd      = (const float*)d_in[9];
    const float* Wr      = (const float*)d_in[10];
    const float* br      = (const float*)d_in[11];
    const float* Wrc     = (const float*)d_in[12];
    const float* brc     = (const float*)d_in[13];
    const float* r_r     = (const float*)d_in[14];
    const float* r_w     = (const float*)d_in[15];
    const float* g_d     = (const float*)d_in[16];
    const float* b_d     = (const float*)d_in[17];
    const float* g_w     = (const float*)d_in[18];
    const float* b_w     = (const float*)d_in[19];
    // d_in[20] (mask) is deterministic -> computed inline in attention

    char* ws = (char*)d_ws;
    size_t off = 0;
    auto alloc = [&](size_t bytes) -> void* {
        void* p = ws + off; off += (bytes + 255) & ~(size_t)255; return p;
    };
    float*  q_ws   = (float*)alloc((size_t)8192 * 1024 * 4);
    float*  kbp    = (float*)alloc((size_t)8192 * 1024 * 4);
    float*  vbp    = (float*)alloc((size_t)8192 * 1024 * 4);
    float*  attn_o = (float*)alloc((size_t)8192 * 1024 * 4);
    float*  kcw    = (float*)alloc((size_t)4 * 128 * 1024 * 4);
    float*  vcw    = (float*)alloc((size_t)4 * 128 * 1024 * 4);
    float*  hcm    = (float*)alloc((size_t)4 * 64 * 1024 * 4);
    float*  kc_raw = (float*)alloc((size_t)4 * 64 * 1024 * 4);
    float*  vc_raw = (float*)alloc((size_t)4 * 64 * 1024 * 4);
    float*  sc_blk = (float*)alloc((size_t)4 * 16 * 64 * 32 * 4);
    float*  k_comp = (float*)alloc((size_t)4 * 128 * 1024 * 4);
    float*  v_comp = (float*)alloc((size_t)4 * 128 * 1024 * 4);
    float2* st_kw  = (float2*)alloc((size_t)4 * 2176 * 8);
    float2* st_vw  = (float2*)alloc((size_t)4 * 2176 * 8);
    float*  pos_tb = (float*)alloc((size_t)128 * 1024 * 4);
    float*  pos_cb = (float*)alloc((size_t)128 * 1024 * 4);

    const dim3 blk(256);

    // projections of h (batch-flattened M=8192)
    gemm_f32<<<dim3(128,16,1), blk, 0, stream>>>(h, 0, Wq, q_ws, 0, 1024, 1024, nullptr, 0.125f);
    gemm_f32<<<dim3(128,16,1), blk, 0, stream>>>(h, 0, Wk, kbp,  0, 1024, 1024, nullptr, 1.f);
    gemm_f32<<<dim3(128,16,1), blk, 0, stream>>>(h, 0, Wv, vbp,  0, 1024, 1024, nullptr, 1.f);
    // window-cache overlap: last W rows of h_cache
    gemm_f32<<<dim3(2,16,4), blk, 0, stream>>>(h_cache + (long)1920 * 1024, (long)2048 * 1024,
                                               Wk, kcw, (long)128 * 1024, 1024, 1024, nullptr, 1.f);
    gemm_f32<<<dim3(2,16,4), blk, 0, stream>>>(h_cache + (long)1920 * 1024, (long)2048 * 1024,
                                               Wv, vcw, (long)128 * 1024, 1024, 1024, nullptr, 1.f);
    // compress cache (scores from h_cache); scores from h (saved for kbp/vbp compress)
    scores_compress<<<dim3(64,4), blk, 0, stream>>>(h_cache, (long)2048 * 1024, Wd, bd,
                                                    hcm, (long)64 * 1024, nullptr, 0);
    scores_compress<<<dim3(64,4), blk, 0, stream>>>(h, (long)2048 * 1024, Wd, bd,
                                                    nullptr, 0, sc_blk, (long)16 * 64 * 32);
    // project compressed cache (M = 4*64 = 256 flattened)
    gemm_f32<<<dim3(4,16,1), blk, 0, stream>>>(hcm, 0, Wk, kc_raw, 0, 1024, 1024, nullptr, 1.f);
    gemm_f32<<<dim3(4,16,1), blk, 0, stream>>>(hcm, 0, Wv, vc_raw, 0, 1024, 1024, nullptr, 1.f);
    // current-block compressed K/V (+LN) -> k_comp/v_comp rows 64..127
    compress_kv_ln<<<dim3(64,4), blk, 0, stream>>>(kbp, vbp, sc_blk, g_d, b_d, k_comp, v_comp);
    // LN of cache compressed K/V -> rows 0..63
    ln_rows<<<dim3(256), blk, 0, stream>>>(kc_raw, (long)64*1024, k_comp, (long)128*1024, 0, 64, g_d, b_d);
    ln_rows<<<dim3(256), blk, 0, stream>>>(vc_raw, (long)64*1024, v_comp, (long)128*1024, 0, 64, g_d, b_d);
    // window LN stats (LN applied on the fly inside attention)
    row_stats<<<dim3(512),  blk, 0, stream>>>(kcw, (long)128*1024,  st_kw, 2176, 0,   128);
    row_stats<<<dim3(512),  blk, 0, stream>>>(vcw, (long)128*1024,  st_vw, 2176, 0,   128);
    row_stats<<<dim3(8192), blk, 0, stream>>>(kbp, (long)2048*1024, st_kw, 2176, 128, 2048);
    row_stats<<<dim3(8192), blk, 0, stream>>>(vbp, (long)2048*1024, st_vw, 2176, 128, 2048);
    // positional projections
    gemm_f32<<<dim3(2,16,1), blk, 0, stream>>>(pos_w,  0, Wr,  pos_tb, 0, 1024, 1024, br,  1.f);
    gemm_f32<<<dim3(2,16,1), blk, 0, stream>>>(key_pe, 0, Wrc, pos_cb, 0, 1024, 1024, brc, 1.f);
    // fused attention
    attention<<<dim3(64,16,4), blk, 0, stream>>>(q_ws, k_comp, v_comp, kcw, vcw, kbp, vbp,
                                                 st_kw, st_vw, g_w, b_w,
                                                 pos_cb, pos_tb, r_w, r_r, attn_o);
    // output projection
    gemm_f32<<<dim3(128,16,1), blk, 0, stream>>>(attn_o, 0, Wo, (float*)d_out, 0, 1024, 1024, nullptr, 1.f);
}

// Round 3
// 1011.226 us; speedup vs baseline: 2.1130x; 2.1130x over previous
//
#include <hip/hip_runtime.h>

// ChunkedLSAttention on MI355X (gfx950).
// B=4, L=2048, D=1024, H=16, DH=64, W=128, CS=32, NCC=NCB=64, NC=128, NQ=64.
// All inputs/outputs f32. bf16 for all MFMA operands (f32 accumulate).
// Mask (d_in[20]) deterministic: masked iff ci-64 >= qc. rel_shift -> pos_c[64+ci-qc].

typedef unsigned short u16;
typedef __attribute__((ext_vector_type(8))) short short8;
typedef __attribute__((ext_vector_type(4))) float f32x4;

#define NEGINF -1e30f

__device__ __forceinline__ float bf2f(u16 u) {
    union { unsigned int i; float f; } v; v.i = ((unsigned int)u) << 16; return v.f;
}
__device__ __forceinline__ u16 f2bf(float f) {
    union { float fl; unsigned int i; } v; v.fl = f;
    unsigned int x = v.i;
    return (u16)((x + 0x7fffu + ((x >> 16) & 1u)) >> 16);   // RNE
}

__device__ __forceinline__ short8 ldg8(const u16* p) {       // 16B-aligned global load
    return *(const short8*)p;
}

// ---------------------------------------------------------------------------
// casts
// ---------------------------------------------------------------------------
__global__ __launch_bounds__(256) void cast_f2b(const float* __restrict__ s,
                                                u16* __restrict__ d, int n4)
{
    int i = blockIdx.x * 256 + threadIdx.x;
    if (i >= n4) return;
    float4 v = ((const float4*)s)[i];
    u16* o = d + i * 4;
    o[0] = f2bf(v.x); o[1] = f2bf(v.y); o[2] = f2bf(v.z); o[3] = f2bf(v.w);
}

// h_cache rows 1920..2047 per batch -> (4,128,1024) bf16
__global__ __launch_bounds__(256) void cast_win(const float* __restrict__ hc,
                                                u16* __restrict__ d)
{
    int i = blockIdx.x * 256 + threadIdx.x;     // f4 units, total 131072
    int flat = i * 4;
    int b = flat >> 17, r = (flat >> 10) & 127, c = flat & 1023;
    float4 v = *(const float4*)(hc + ((long)b * 2048 + 1920 + r) * 1024 + c);
    u16* o = d + (long)flat;
    o[0] = f2bf(v.x); o[1] = f2bf(v.y); o[2] = f2bf(v.z); o[3] = f2bf(v.w);
}

// ---------------------------------------------------------------------------
// GEMM: C = A(bf16,MxK) @ B(bf16,KxN) * scale + bias ; optional f32/bf16 out.
// Block 256 = 4 waves, tile 64x64, K-chunk 32, mfma_f32_16x16x32_bf16.
// A frag A[m=lane&15][k=quad*8+j]; B frag B[k][n=lane&15] (Bs transposed);
// D: col=lane&15, row=quad*4+r.
// ---------------------------------------------------------------------------
__global__ __launch_bounds__(256) void gemm_bf16(
    const u16* __restrict__ A, long a_bstride,
    const u16* __restrict__ Bm,
    float* __restrict__ Cf, u16* __restrict__ Cb, long c_bstride,
    int N, int K, const float* __restrict__ bias, float scale)
{
    const int tid = threadIdx.x;
    const int bm = blockIdx.x, bn = blockIdx.y, bz = blockIdx.z;
    A += (long)bz * a_bstride;
    const long coff = (long)bz * c_bstride;

    __shared__ __align__(16) u16 As[64][40];
    __shared__ __align__(16) u16 Bs[64][40];

    const int lane = tid & 63, wv = tid >> 6;
    const int wm = (wv & 1) * 32, wn = (wv >> 1) * 32;
    const int l15 = lane & 15, quad = lane >> 4;

    f32x4 acc00 = {0.f,0.f,0.f,0.f}, acc01 = {0.f,0.f,0.f,0.f};
    f32x4 acc10 = {0.f,0.f,0.f,0.f}, acc11 = {0.f,0.f,0.f,0.f};

    const int row_a = tid >> 2, col_a = (tid & 3) * 8;
    const int row_b = tid >> 3, col_b = (tid & 7) * 8;
    const u16* a_src = A + (long)(bm * 64 + row_a) * K + col_a;
    const u16* b_src = Bm + (long)row_b * N + bn * 64 + col_b;

    for (int k0 = 0; k0 < K; k0 += 32) {
        int4 av = *(const int4*)a_src; a_src += 32;
        int4 bv = *(const int4*)b_src; b_src += 32 * (long)N;
        __syncthreads();
        *(int4*)&As[row_a][col_a] = av;
        const u16* bw = (const u16*)&bv;
        #pragma unroll
        for (int e = 0; e < 8; ++e) Bs[col_b + e][row_b] = bw[e];
        __syncthreads();

        short8 a0 = *(const short8*)&As[wm + l15][quad * 8];
        short8 a1 = *(const short8*)&As[wm + 16 + l15][quad * 8];
        short8 b0 = *(const short8*)&Bs[wn + l15][quad * 8];
        short8 b1 = *(const short8*)&Bs[wn + 16 + l15][quad * 8];
        acc00 = __builtin_amdgcn_mfma_f32_16x16x32_bf16(a0, b0, acc00, 0, 0, 0);
        acc01 = __builtin_amdgcn_mfma_f32_16x16x32_bf16(a0, b1, acc01, 0, 0, 0);
        acc10 = __builtin_amdgcn_mfma_f32_16x16x32_bf16(a1, b0, acc10, 0, 0, 0);
        acc11 = __builtin_amdgcn_mfma_f32_16x16x32_bf16(a1, b1, acc11, 0, 0, 0);
    }

    f32x4 accs[2][2] = {{acc00, acc01}, {acc10, acc11}};
    #pragma unroll
    for (int i = 0; i < 2; ++i) {
        #pragma unroll
        for (int j = 0; j < 2; ++j) {
            int col = bn * 64 + wn + j * 16 + l15;
            float bsv = bias ? bias[col] : 0.f;
            #pragma unroll
            for (int r = 0; r < 4; ++r) {
                int row = bm * 64 + wm + i * 16 + quad * 4 + r;
                float v = accs[i][j][r] * scale + bsv;
                long idx = coff + (long)row * N + col;
                if (Cf) Cf[idx] = v;
                if (Cb) Cb[idx] = f2bf(v);
            }
        }
    }
}

// ---------------------------------------------------------------------------
// Per-chunk head scores (+softmax over 32 rows) and optional compress of src.
// grid=(64, B), block 256.
// ---------------------------------------------------------------------------
__global__ __launch_bounds__(256) void scores_compress(
    const float* __restrict__ src, long src_bstride,
    const float* __restrict__ Wd, const float* __restrict__ bd,
    u16* __restrict__ out_comp, long comp_bstride,
    float* __restrict__ out_sc, long sc_bstride)
{
    const int c = blockIdx.x, b = blockIdx.y;
    const int tid = threadIdx.x;

    __shared__ __align__(16) u16 srcs[32][1032];
    __shared__ float s_sm[32][16];

    const float* sb = src + (long)b * src_bstride + (long)c * 32 * 1024;
    for (int e = tid; e < 8192; e += 256) {
        int flat = e * 4;
        int row = flat >> 10, col = flat & 1023;
        float4 v = *(const float4*)(sb + (long)row * 1024 + col);
        u16* dp = &srcs[row][col];
        dp[0] = f2bf(v.x); dp[1] = f2bf(v.y); dp[2] = f2bf(v.z); dp[3] = f2bf(v.w);
    }
    __syncthreads();

    {
        int i = tid >> 3;
        int hd0 = (tid & 7) * 2;
        float acc0 = bd[hd0], acc1 = bd[hd0 + 1];
        for (int d = 0; d < 1024; ++d) {
            float xv = bf2f(srcs[i][d]);
            float2 wp = *(const float2*)(Wd + d * 16 + hd0);
            acc0 += xv * wp.x;
            acc1 += xv * wp.y;
        }
        s_sm[i][hd0] = acc0;
        s_sm[i][hd0 + 1] = acc1;
    }
    __syncthreads();

    if (tid < 16) {
        int hd = tid;
        float m = NEGINF;
        for (int i = 0; i < 32; ++i) m = fmaxf(m, s_sm[i][hd]);
        float s = 0.f;
        for (int i = 0; i < 32; ++i) s += __expf(s_sm[i][hd] - m);
        float inv = 1.f / s;
        for (int i = 0; i < 32; ++i) s_sm[i][hd] = __expf(s_sm[i][hd] - m) * inv;
    }
    __syncthreads();

    if (out_sc) {
        for (int idx = tid; idx < 512; idx += 256) {
            int hd = idx >> 5, i = idx & 31;
            out_sc[(long)b * sc_bstride + ((long)hd * 64 + c) * 32 + i] = s_sm[i][hd];
        }
    }
    if (out_comp) {
        #pragma unroll
        for (int p = 0; p < 4; ++p) {
            int j = tid + p * 256;
            int hd = j >> 6;
            float acc = 0.f;
            for (int i = 0; i < 32; ++i) acc += s_sm[i][hd] * bf2f(srcs[i][j]);
            out_comp[(long)b * comp_bstride + (long)c * 1024 + j] = f2bf(acc);
        }
    }
}

// ---------------------------------------------------------------------------
// Compress projected k_bp/v_bp with block scores, LN -> k_comp rows 64..127
// (bf16 normal) and vcT cols 64..127 (bf16 transposed (B,1024,128)).
// grid=(64, B), block 256.
// ---------------------------------------------------------------------------
__global__ __launch_bounds__(256) void compress_kv_ln(
    const float* __restrict__ kbp, const float* __restrict__ vbp,
    const float* __restrict__ sc,
    const float* __restrict__ g, const float* __restrict__ be,
    u16* __restrict__ k_comp, u16* __restrict__ vcT)
{
    const int c = blockIdx.x, b = blockIdx.y;
    const int tid = threadIdx.x;
    const int lane = tid & 63, wv = tid >> 6;

    __shared__ float scw[16][32];
    __shared__ float red[4][4];

    for (int idx = tid; idx < 512; idx += 256) {
        int hd = idx >> 5, i = idx & 31;
        scw[hd][i] = sc[((long)(b * 16 + hd) * 64 + c) * 32 + i];
    }
    __syncthreads();

    float xk[4], xv[4];
    #pragma unroll
    for (int p = 0; p < 4; ++p) {
        int j = tid + p * 256;
        int hd = j >> 6;
        float ak = 0.f, av = 0.f;
        for (int i = 0; i < 32; ++i) {
            float w = scw[hd][i];
            long off = ((long)b * 2048 + c * 32 + i) * 1024 + j;
            ak += w * kbp[off];
            av += w * vbp[off];
        }
        xk[p] = ak; xv[p] = av;
    }
    float sk = 0.f, qk = 0.f, sv = 0.f, qv = 0.f;
    #pragma unroll
    for (int p = 0; p < 4; ++p) { sk += xk[p]; qk += xk[p]*xk[p]; sv += xv[p]; qv += xv[p]*xv[p]; }
    for (int off = 32; off; off >>= 1) {
        sk += __shfl_xor(sk, off); qk += __shfl_xor(qk, off);
        sv += __shfl_xor(sv, off); qv += __shfl_xor(qv, off);
    }
    if (lane == 0) { red[0][wv] = sk; red[1][wv] = qk; red[2][wv] = sv; red[3][wv] = qv; }
    __syncthreads();
    sk = red[0][0] + red[0][1] + red[0][2] + red[0][3];
    qk = red[1][0] + red[1][1] + red[1][2] + red[1][3];
    sv = red[2][0] + red[2][1] + red[2][2] + red[2][3];
    qv = red[3][0] + red[3][1] + red[3][2] + red[3][3];
    const float inv_n = 1.f / 1024.f;
    float mk = sk * inv_n, mv = sv * inv_n;
    float ik = rsqrtf(fmaxf(qk * inv_n - mk * mk, 0.f) + 1e-5f);
    float iv = rsqrtf(fmaxf(qv * inv_n - mv * mv, 0.f) + 1e-5f);
    #pragma unroll
    for (int p = 0; p < 4; ++p) {
        int j = tid + p * 256;
        k_comp[((long)b * 128 + 64 + c) * 1024 + j] = f2bf((xk[p] - mk) * ik * g[j] + be[j]);
        vcT[((long)b * 1024 + j) * 128 + 64 + c]   = f2bf((xv[p] - mv) * iv * g[j] + be[j]);
    }
}

// ---------------------------------------------------------------------------
// Row LN (D=1024) -> bf16 normal (dstN) and/or bf16 transposed (dstT, (B,1024,128)).
// grid.x = B * rows_per_batch, block 256.
// ---------------------------------------------------------------------------
__global__ __launch_bounds__(256) void ln_rows(
    const float* __restrict__ src, long src_bstride,
    u16* __restrict__ dstN, long dstN_bstride, long dstN_rowoff,
    u16* __restrict__ dstT, long dstT_coloff,
    int rows_per_batch,
    const float* __restrict__ g, const float* __restrict__ be)
{
    const int gr = blockIdx.x;
    const int b = gr / rows_per_batch, r = gr % rows_per_batch;
    const float* s = src + (long)b * src_bstride + (long)r * 1024;
    const int tid = threadIdx.x;
    const int lane = tid & 63, wv = tid >> 6;

    __shared__ float red[2][4];
    float x[4];
    float sm = 0.f, sq = 0.f;
    #pragma unroll
    for (int p = 0; p < 4; ++p) {
        x[p] = s[tid + p * 256];
        sm += x[p]; sq += x[p] * x[p];
    }
    for (int off = 32; off; off >>= 1) { sm += __shfl_xor(sm, off); sq += __shfl_xor(sq, off); }
    if (lane == 0) { red[0][wv] = sm; red[1][wv] = sq; }
    __syncthreads();
    sm = red[0][0] + red[0][1] + red[0][2] + red[0][3];
    sq = red[1][0] + red[1][1] + red[1][2] + red[1][3];
    float m = sm * (1.f / 1024.f);
    float inv = rsqrtf(fmaxf(sq * (1.f / 1024.f) - m * m, 0.f) + 1e-5f);
    #pragma unroll
    for (int p = 0; p < 4; ++p) {
        int j = tid + p * 256;
        u16 o = f2bf((x[p] - m) * inv * g[j] + be[j]);
        if (dstN) dstN[(long)b * dstN_bstride + (dstN_rowoff + r) * 1024 + j] = o;
        if (dstT) dstT[((long)b * 1024 + j) * 128 + dstT_coloff + r] = o;
    }
}

// ---------------------------------------------------------------------------
// Per-row mean/rstd (D=1024). grid.x = B*rows, block 256.
// ---------------------------------------------------------------------------
__global__ __launch_bounds__(256) void row_stats(
    const float* __restrict__ src, long src_bstride,
    float2* __restrict__ dst, long dst_bstride, long dst_row_off,
    int rows_per_batch)
{
    const int gr = blockIdx.x;
    const int b = gr / rows_per_batch, r = gr % rows_per_batch;
    const float* s = src + (long)b * src_bstride + (long)r * 1024;
    const int tid = threadIdx.x;
    const int lane = tid & 63, wv = tid >> 6;

    __shared__ float red[2][4];
    float sm = 0.f, sq = 0.f;
    #pragma unroll
    for (int p = 0; p < 4; ++p) {
        float x = s[tid + p * 256];
        sm += x; sq += x * x;
    }
    for (int off = 32; off; off >>= 1) { sm += __shfl_xor(sm, off); sq += __shfl_xor(sq, off); }
    if (lane == 0) { red[0][wv] = sm; red[1][wv] = sq; }
    __syncthreads();
    if (tid == 0) {
        sm = red[0][0] + red[0][1] + red[0][2] + red[0][3];
        sq = red[1][0] + red[1][1] + red[1][2] + red[1][3];
        float m = sm * (1.f / 1024.f);
        float inv = rsqrtf(fmaxf(sq * (1.f / 1024.f) - m * m, 0.f) + 1e-5f);
        dst[(long)b * dst_bstride + dst_row_off + r] = make_float2(m, inv);
    }
}

// ---------------------------------------------------------------------------
// Materialize window K (bf16, (B,2176,1024)) and V^T (bf16, (B,1024,2176),
// col = concat_row - 1 so attention B-loads are 16B aligned).
// grid=(34, 16, B): 64 rows x 64 dims per block.
// ---------------------------------------------------------------------------
__global__ __launch_bounds__(256) void win_apply(
    const float* __restrict__ kcw, const float* __restrict__ vcw,
    const float* __restrict__ kbp, const float* __restrict__ vbp,
    const float2* __restrict__ st_kw, const float2* __restrict__ st_vw,
    const float* __restrict__ g_w, const float* __restrict__ b_w,
    u16* __restrict__ kwin, u16* __restrict__ vwinT)
{
    const int tt = blockIdx.x, dc = blockIdx.y, b = blockIdx.z;
    const int t0 = tt * 64, d0 = dc * 64;
    const int tid = threadIdx.x;

    __shared__ u16 vt[64][74];

    const int r = tid >> 2;
    const int dsub = (tid & 3) * 16;
    const int t = t0 + r;
    const float* ks; const float* vs;
    if (t < 128) {
        ks = kcw + ((long)b * 128 + t) * 1024;
        vs = vcw + ((long)b * 128 + t) * 1024;
    } else {
        ks = kbp + ((long)b * 2048 + t - 128) * 1024;
        vs = vbp + ((long)b * 2048 + t - 128) * 1024;
    }
    float2 sk = st_kw[(long)b * 2176 + t];
    float2 sv = st_vw[(long)b * 2176 + t];
    #pragma unroll
    for (int j = 0; j < 16; j += 4) {
        int d = d0 + dsub + j;
        float4 kv = *(const float4*)(ks + d);
        float4 vv = *(const float4*)(vs + d);
        float4 g4 = *(const float4*)(g_w + d);
        float4 b4 = *(const float4*)(b_w + d);
        u16 ko[4];
        ko[0] = f2bf((kv.x - sk.x) * sk.y * g4.x + b4.x);
        ko[1] = f2bf((kv.y - sk.x) * sk.y * g4.y + b4.y);
        ko[2] = f2bf((kv.z - sk.x) * sk.y * g4.z + b4.z);
        ko[3] = f2bf((kv.w - sk.x) * sk.y * g4.w + b4.w);
        *(uint2*)&kwin[((long)b * 2176 + t) * 1024 + d] = *(const uint2*)ko;
        vt[r][dsub + j + 0] = f2bf((vv.x - sv.x) * sv.y * g4.x + b4.x);
        vt[r][dsub + j + 1] = f2bf((vv.y - sv.x) * sv.y * g4.y + b4.y);
        vt[r][dsub + j + 2] = f2bf((vv.z - sv.x) * sv.y * g4.z + b4.z);
        vt[r][dsub + j + 3] = f2bf((vv.w - sv.x) * sv.y * g4.w + b4.w);
    }
    __syncthreads();
    #pragma unroll
    for (int pass = 0; pass < 16; ++pass) {
        int dd = (tid >> 6) + pass * 4;
        int rr = tid & 63;
        int crow = t0 + rr;
        if (crow >= 1)
            vwinT[((long)b * 1024 + d0 + dd) * 2176 + crow - 1] = vt[rr][dd];
    }
}

// ---------------------------------------------------------------------------
// Fused MFMA attention: one block per (qc, h, b), 256 thr = 4 waves.
// Rectangular MFMA for all score/PV parts; band shift applied in LDS.
// ---------------------------------------------------------------------------
__global__ __launch_bounds__(256) void attention(
    const u16* __restrict__ qb,     // (B,2048,1024) bf16, already /8
    const u16* __restrict__ kcb,    // (B,128,1024) bf16
    const u16* __restrict__ vcT,    // (B,1024,128) bf16 transposed
    const u16* __restrict__ kwb,    // (B,2176,1024) bf16
    const u16* __restrict__ vwT,    // (B,1024,2176) bf16 transposed, col=row-1
    const u16* __restrict__ pcb,    // (128,1024) bf16
    const u16* __restrict__ ptb,    // (128,1024) bf16
    const float* __restrict__ r_w,  // (16,64)
    const float* __restrict__ r_r,
    u16* __restrict__ attn_o)       // (B,2048,1024) bf16
{
    const int qc = blockIdx.x, h = blockIdx.y, b = blockIdx.z;
    const int l0 = qc * 32;
    const int tid = threadIdx.x;
    const int lane = tid & 63, wv = tid >> 6;
    const int l15 = lane & 15, quad = lane >> 4;

    __shared__ __align__(16) u16 qa[3][32][72];   // 0:q  1:q+r_w  2:q+r_r
    __shared__ float logits[32][264];             // cols 0..127 comp, 128..255 win
    __shared__ float redm[4][32], reds[4][32];

    // ---- stage q ----
    for (int e = tid; e < 2048; e += 256) {
        int r = e >> 6, d = e & 63;
        u16 qv = qb[((long)(b * 2048 + l0 + r)) * 1024 + h * 64 + d];
        float qf = bf2f(qv);
        qa[0][r][d] = qv;
        qa[1][r][d] = f2bf(qf + r_w[h * 64 + d]);
        qa[2][r][d] = f2bf(qf + r_r[h * 64 + d]);
    }
    __syncthreads();

    // ---- S_c: q·k_comp + q·pos_c[64+ci-qc], tiles 2wv..2wv+1 ----
    #pragma unroll
    for (int ti = 0; ti < 2; ++ti) {
        int n0 = (wv * 2 + ti) * 16;
        int ci = n0 + l15;
        f32x4 a0 = {0.f,0.f,0.f,0.f}, a1 = {0.f,0.f,0.f,0.f};
        if (n0 < 64 + qc) {
            int p = 64 + ci - qc; if (p > 127) p = 127;
            #pragma unroll
            for (int kc = 0; kc < 2; ++kc) {
                int k0 = kc * 32;
                short8 bk = ldg8(kcb + ((long)(b * 128 + ci)) * 1024 + h * 64 + k0 + quad * 8);
                short8 bp = ldg8(pcb + (long)p * 1024 + h * 64 + k0 + quad * 8);
                short8 fa0 = *(const short8*)&qa[0][l15][k0 + quad * 8];
                short8 fa1 = *(const short8*)&qa[0][16 + l15][k0 + quad * 8];
                a0 = __builtin_amdgcn_mfma_f32_16x16x32_bf16(fa0, bk, a0, 0, 0, 0);
                a0 = __builtin_amdgcn_mfma_f32_16x16x32_bf16(fa0, bp, a0, 0, 0, 0);
                a1 = __builtin_amdgcn_mfma_f32_16x16x32_bf16(fa1, bk, a1, 0, 0, 0);
                a1 = __builtin_amdgcn_mfma_f32_16x16x32_bf16(fa1, bp, a1, 0, 0, 0);
            }
        }
        bool msk = (ci >= 64 + qc);
        #pragma unroll
        for (int r = 0; r < 4; ++r) {
            logits[quad * 4 + r][ci]      = msk ? NEGINF : a0[r];
            logits[16 + quad * 4 + r][ci] = msk ? NEGINF : a1[r];
        }
    }

    // ---- S2: (q+r_r)·pos_t, tiles 2wv..2wv+1 ----
    #pragma unroll
    for (int ti = 0; ti < 2; ++ti) {
        int w0 = (wv * 2 + ti) * 16;
        int w = w0 + l15;
        f32x4 a0 = {0.f,0.f,0.f,0.f}, a1 = {0.f,0.f,0.f,0.f};
        #pragma unroll
        for (int kc = 0; kc < 2; ++kc) {
            int k0 = kc * 32;
            short8 bp = ldg8(ptb + (long)w * 1024 + h * 64 + k0 + quad * 8);
            short8 fa0 = *(const short8*)&qa[2][l15][k0 + quad * 8];
            short8 fa1 = *(const short8*)&qa[2][16 + l15][k0 + quad * 8];
            a0 = __builtin_amdgcn_mfma_f32_16x16x32_bf16(fa0, bp, a0, 0, 0, 0);
            a1 = __builtin_amdgcn_mfma_f32_16x16x32_bf16(fa1, bp, a1, 0, 0, 0);
        }
        #pragma unroll
        for (int r = 0; r < 4; ++r) {
            logits[quad * 4 + r][128 + w]      = a0[r];
            logits[16 + quad * 4 + r][128 + w] = a1[r];
        }
    }

    // ---- S1: (q+r_w)·k_win[l0+1+t], t tiles wv, wv+4, wv+8 (<10); regs ----
    f32x4 s1a[3], s1b[3];
    int nts[3]; int nw = 0;
    for (int nt = wv; nt < 10; nt += 4) {
        int t = nt * 16 + l15;
        int row = l0 + 1 + t; if (row > 2175) row = 2175;
        f32x4 a0 = {0.f,0.f,0.f,0.f}, a1 = {0.f,0.f,0.f,0.f};
        #pragma unroll
        for (int kc = 0; kc < 2; ++kc) {
            int k0 = kc * 32;
            short8 bk = ldg8(kwb + ((long)(b * 2176 + row)) * 1024 + h * 64 + k0 + quad * 8);
            short8 fa0 = *(const short8*)&qa[1][l15][k0 + quad * 8];
            short8 fa1 = *(const short8*)&qa[1][16 + l15][k0 + quad * 8];
            a0 = __builtin_amdgcn_mfma_f32_16x16x32_bf16(fa0, bk, a0, 0, 0, 0);
            a1 = __builtin_amdgcn_mfma_f32_16x16x32_bf16(fa1, bk, a1, 0, 0, 0);
        }
        s1a[nw] = a0; s1b[nw] = a1; nts[nw] = nt; ++nw;
    }
    __syncthreads();
    // band add: logits[row][128 + (t-row)] += S1
    for (int i = 0; i < nw; ++i) {
        int t = nts[i] * 16 + l15;
        #pragma unroll
        for (int r = 0; r < 4; ++r) {
            int r0 = quad * 4 + r;
            int w0 = t - r0;
            if (w0 >= 0 && w0 < 128) logits[r0][128 + w0] += s1a[i][r];
            int r1 = 16 + quad * 4 + r;
            int w1 = t - r1;
            if (w1 >= 0 && w1 < 128) logits[r1][128 + w1] += s1b[i][r];
        }
    }
    __syncthreads();

    // ---- softmax over 256 cols (tid = col) ----
    for (int r = 0; r < 32; ++r) {
        float v = logits[r][tid];
        for (int off = 32; off; off >>= 1) v = fmaxf(v, __shfl_xor(v, off));
        if (lane == 0) redm[wv][r] = v;
    }
    __syncthreads();
    for (int r = 0; r < 32; ++r) {
        float M = fmaxf(fmaxf(redm[0][r], redm[1][r]), fmaxf(redm[2][r], redm[3][r]));
        float e = __expf(logits[r][tid] - M);
        logits[r][tid] = e;
        float s = e;
        for (int off = 32; off; off >>= 1) s += __shfl_xor(s, off);
        if (lane == 0) reds[wv][r] = s;
    }
    __syncthreads();
    for (int r = 0; r < 32; ++r) {
        float S = reds[0][r] + reds[1][r] + reds[2][r] + reds[3][r];
        logits[r][tid] = logits[r][tid] / S;
    }
    __syncthreads();

    // ---- PV: wave wv -> d-tile wv*16 ----
    const int n0d = wv * 16;
    f32x4 o0 = {0.f,0.f,0.f,0.f}, o1 = {0.f,0.f,0.f,0.f};
    // compressed: K=128
    #pragma unroll
    for (int kc = 0; kc < 4; ++kc) {
        int k0 = kc * 32;
        short8 bv = ldg8(vcT + ((long)(b * 1024 + h * 64 + n0d + l15)) * 128 + k0 + quad * 8);
        short8 av0, av1;
        #pragma unroll
        for (int j = 0; j < 8; ++j) {
            av0[j] = (short)f2bf(logits[l15][k0 + quad * 8 + j]);
            av1[j] = (short)f2bf(logits[16 + l15][k0 + quad * 8 + j]);
        }
        o0 = __builtin_amdgcn_mfma_f32_16x16x32_bf16(av0, bv, o0, 0, 0, 0);
        o1 = __builtin_amdgcn_mfma_f32_16x16x32_bf16(av1, bv, o1, 0, 0, 0);
    }
    // windowed: K=160 (t), P[m][t] = p[m][t-m] banded
    #pragma unroll
    for (int kc = 0; kc < 5; ++kc) {
        int k0 = kc * 32;
        short8 bv = ldg8(vwT + ((long)(b * 1024 + h * 64 + n0d + l15)) * 2176 + l0 + k0 + quad * 8);
        short8 av0, av1;
        #pragma unroll
        for (int j = 0; j < 8; ++j) {
            int t = k0 + quad * 8 + j;
            int w0 = t - l15;
            int w1 = t - (16 + l15);
            av0[j] = (w0 >= 0 && w0 < 128) ? (short)f2bf(logits[l15][128 + w0]) : (short)0;
            av1[j] = (w1 >= 0 && w1 < 128) ? (short)f2bf(logits[16 + l15][128 + w1]) : (short)0;
        }
        o0 = __builtin_amdgcn_mfma_f32_16x16x32_bf16(av0, bv, o0, 0, 0, 0);
        o1 = __builtin_amdgcn_mfma_f32_16x16x32_bf16(av1, bv, o1, 0, 0, 0);
    }
    // store
    #pragma unroll
    for (int r = 0; r < 4; ++r) {
        int r0 = quad * 4 + r, r1 = 16 + quad * 4 + r;
        attn_o[((long)(b * 2048 + l0 + r0)) * 1024 + h * 64 + n0d + l15] = f2bf(o0[r]);
        attn_o[((long)(b * 2048 + l0 + r1)) * 1024 + h * 64 + n0d + l15] = f2bf(o1[r]);
    }
}

// ---------------------------------------------------------------------------
extern "C" void kernel_launch(void* const* d_in, const int* in_sizes, int n_in,
                              void* d_out, int out_size, void* d_ws, size_t ws_size,
                              hipStream_t stream)
{
    (void)in_sizes; (void)n_in; (void)out_size; (void)ws_size;

    const float* h       = (const float*)d_in[0];
    const float* h_cache = (const float*)d_in[1];
    const float* key_pe  = (const float*)d_in[2];
    const float* pos_w   = (const float*)d_in[3];
    const float* Wq      = (const float*)d_in[4];
    const float* Wk      = (const float*)d_in[5];
    const float* Wv      = (const float*)d_in[6];
    const float* Wo      = (const float*)d_in[7];
    const float* Wd      = (const float*)d_in[8];
    const float* bd      = (const float*)d_in[9];
    const float* Wr      = (const float*)d_in[10];
    const float* br      = (const float*)d_in[11];
    const float* Wrc     = (const float*)d_in[12];
    const float* brc     = (const float*)d_in[13];
    const float* r_r     = (const float*)d_in[14];
    const float* r_w     = (const float*)d_in[15];
    const float* g_d     = (const float*)d_in[16];
    const float* b_d     = (const float*)d_in[17];
    const float* g_w     = (const float*)d_in[18];
    const float* b_w     = (const float*)d_in[19];

    char* ws = (char*)d_ws;
    size_t off = 0;
    auto alloc = [&](size_t bytes) -> void* {
        void* p = ws + off; off += (bytes + 255) & ~(size_t)255; return p;
    };
    // bf16 casts
    u16* hB    = (u16*)alloc((size_t)8192 * 1024 * 2);
    u16* hcwB  = (u16*)alloc((size_t)4 * 128 * 1024 * 2);
    u16* WqB   = (u16*)alloc((size_t)1024 * 1024 * 2);
    u16* WkB   = (u16*)alloc((size_t)1024 * 1024 * 2);
    u16* WvB   = (u16*)alloc((size_t)1024 * 1024 * 2);
    u16* WoB   = (u16*)alloc((size_t)1024 * 1024 * 2);
    u16* WrB   = (u16*)alloc((size_t)1024 * 1024 * 2);
    u16* WrcB  = (u16*)alloc((size_t)1024 * 1024 * 2);
    u16* pwB   = (u16*)alloc((size_t)128 * 1024 * 2);
    u16* kpeB  = (u16*)alloc((size_t)128 * 1024 * 2);
    // intermediates
    u16*   q_ws   = (u16*)alloc((size_t)8192 * 1024 * 2);
    float* kbp    = (float*)alloc((size_t)8192 * 1024 * 4);
    float* vbp    = (float*)alloc((size_t)8192 * 1024 * 4);
    u16*   attn_o = (u16*)alloc((size_t)8192 * 1024 * 2);
    float* kcw    = (float*)alloc((size_t)4 * 128 * 1024 * 4);
    float* vcw    = (float*)alloc((size_t)4 * 128 * 1024 * 4);
    u16*   hcm    = (u16*)alloc((size_t)4 * 64 * 1024 * 2);
    float* kc_raw = (float*)alloc((size_t)4 * 64 * 1024 * 4);
    float* vc_raw = (float*)alloc((size_t)4 * 64 * 1024 * 4);
    float* sc_blk = (float*)alloc((size_t)4 * 16 * 64 * 32 * 4);
    u16*   k_comp = (u16*)alloc((size_t)4 * 128 * 1024 * 2);
    u16*   vcT    = (u16*)alloc((size_t)4 * 1024 * 128 * 2);
    float2* st_kw = (float2*)alloc((size_t)4 * 2176 * 8);
    float2* st_vw = (float2*)alloc((size_t)4 * 2176 * 8);
    u16*   pos_tb = (u16*)alloc((size_t)128 * 1024 * 2);
    u16*   pos_cb = (u16*)alloc((size_t)128 * 1024 * 2);
    u16*   kwin   = (u16*)alloc((size_t)4 * 2176 * 1024 * 2);
    u16*   vwinT  = (u16*)alloc((size_t)4 * 1024 * 2176 * 2 + 256);

    const dim3 blk(256);

    // casts
    cast_f2b<<<dim3(8192), blk, 0, stream>>>(h, hB, 2097152);
    cast_win<<<dim3(512), blk, 0, stream>>>(h_cache, hcwB);
    cast_f2b<<<dim3(1024), blk, 0, stream>>>(Wq, WqB, 262144);
    cast_f2b<<<dim3(1024), blk, 0, stream>>>(Wk, WkB, 262144);
    cast_f2b<<<dim3(1024), blk, 0, stream>>>(Wv, WvB, 262144);
    cast_f2b<<<dim3(1024), blk, 0, stream>>>(Wo, WoB, 262144);
    cast_f2b<<<dim3(1024), blk, 0, stream>>>(Wr, WrB, 262144);
    cast_f2b<<<dim3(1024), blk, 0, stream>>>(Wrc, WrcB, 262144);
    cast_f2b<<<dim3(128), blk, 0, stream>>>(pos_w, pwB, 32768);
    cast_f2b<<<dim3(128), blk, 0, stream>>>(key_pe, kpeB, 32768);

    // projections
    gemm_bf16<<<dim3(128,16,1), blk, 0, stream>>>(hB, 0, WqB, nullptr, q_ws, 0, 1024, 1024, nullptr, 0.125f);
    gemm_bf16<<<dim3(128,16,1), blk, 0, stream>>>(hB, 0, WkB, kbp, nullptr, 0, 1024, 1024, nullptr, 1.f);
    gemm_bf16<<<dim3(128,16,1), blk, 0, stream>>>(hB, 0, WvB, vbp, nullptr, 0, 1024, 1024, nullptr, 1.f);
    gemm_bf16<<<dim3(2,16,4), blk, 0, stream>>>(hcwB, (long)128*1024, WkB, kcw, nullptr, (long)128*1024, 1024, 1024, nullptr, 1.f);
    gemm_bf16<<<dim3(2,16,4), blk, 0, stream>>>(hcwB, (long)128*1024, WvB, vcw, nullptr, (long)128*1024, 1024, 1024, nullptr, 1.f);

    // scores + compress
    scores_compress<<<dim3(64,4), blk, 0, stream>>>(h_cache, (long)2048*1024, Wd, bd,
                                                    hcm, (long)64*1024, nullptr, 0);
    scores_compress<<<dim3(64,4), blk, 0, stream>>>(h, (long)2048*1024, Wd, bd,
                                                    nullptr, 0, sc_blk, (long)16*64*32);
    gemm_bf16<<<dim3(4,16,1), blk, 0, stream>>>(hcm, 0, WkB, kc_raw, nullptr, 0, 1024, 1024, nullptr, 1.f);
    gemm_bf16<<<dim3(4,16,1), blk, 0, stream>>>(hcm, 0, WvB, vc_raw, nullptr, 0, 1024, 1024, nullptr, 1.f);

    compress_kv_ln<<<dim3(64,4), blk, 0, stream>>>(kbp, vbp, sc_blk, g_d, b_d, k_comp, vcT);
    ln_rows<<<dim3(256), blk, 0, stream>>>(kc_raw, (long)64*1024, k_comp, (long)128*1024, 0, nullptr, 0, 64, g_d, b_d);
    ln_rows<<<dim3(256), blk, 0, stream>>>(vc_raw, (long)64*1024, nullptr, 0, 0, vcT, 0, 64, g_d, b_d);

    // window LN
    row_stats<<<dim3(512),  blk, 0, stream>>>(kcw, (long)128*1024,  st_kw, 2176, 0,   128);
    row_stats<<<dim3(512),  blk, 0, stream>>>(vcw, (long)128*1024,  st_vw, 2176, 0,   128);
    row_stats<<<dim3(8192), blk, 0, stream>>>(kbp, (long)2048*1024, st_kw, 2176, 128, 2048);
    row_stats<<<dim3(8192), blk, 0, stream>>>(vbp, (long)2048*1024, st_vw, 2176, 128, 2048);
    win_apply<<<dim3(34,16,4), blk, 0, stream>>>(kcw, vcw, kbp, vbp, st_kw, st_vw, g_w, b_w, kwin, vwinT);

    // positional projections
    gemm_bf16<<<dim3(2,16,1), blk, 0, stream>>>(pwB,  0, WrB,  nullptr, pos_tb, 0, 1024, 1024, br,  1.f);
    gemm_bf16<<<dim3(2,16,1), blk, 0, stream>>>(kpeB, 0, WrcB, nullptr, pos_cb, 0, 1024, 1024, brc, 1.f);

    // attention
    attention<<<dim3(64,16,4), blk, 0, stream>>>(q_ws, k_comp, vcT, kwin, vwinT,
                                                 pos_cb, pos_tb, r_w, r_r, attn_o);
    // output projection
    gemm_bf16<<<dim3(128,16,1), blk, 0, stream>>>(attn_o, 0, WoB, (float*)d_out, nullptr, 0, 1024, 1024, nullptr, 1.f);
}

// Round 4
// 814.211 us; speedup vs baseline: 2.6242x; 1.2420x over previous
//
#include <hip/hip_runtime.h>

// ChunkedLSAttention on MI355X (gfx950).
// B=4, L=2048, D=1024, H=16, DH=64, W=128, CS=32, NCC=NCB=64, NC=128, NQ=64.
// All inputs/outputs f32. bf16 for all MFMA operands (f32 accumulate).
// Mask (d_in[20]) deterministic: masked iff ci-64 >= qc. rel_shift -> pos_c[64+ci-qc].

typedef unsigned short u16;
typedef __attribute__((ext_vector_type(8))) short short8;
typedef __attribute__((ext_vector_type(4))) float f32x4;

#define NEGINF -1e30f

__device__ __forceinline__ float bf2f(u16 u) {
    union { unsigned int i; float f; } v; v.i = ((unsigned int)u) << 16; return v.f;
}
__device__ __forceinline__ u16 f2bf(float f) {
    union { float fl; unsigned int i; } v; v.fl = f;
    unsigned int x = v.i;
    return (u16)((x + 0x7fffu + ((x >> 16) & 1u)) >> 16);   // RNE
}
__device__ __forceinline__ short8 ldg8(const u16* p) { return *(const short8*)p; }

// async global->LDS, 16B per lane; LDS dest = wave-uniform base + lane*16.
__device__ __forceinline__ void async16(const u16* g, u16* l) {
    __builtin_amdgcn_global_load_lds(
        (const __attribute__((address_space(1))) unsigned int*)g,
        (__attribute__((address_space(3))) unsigned int*)l, 16, 0, 0);
}

// ---------------------------------------------------------------------------
// casts
// ---------------------------------------------------------------------------
__global__ __launch_bounds__(256) void cast_f2b(const float* __restrict__ s,
                                                u16* __restrict__ d, int n4)
{
    int i = blockIdx.x * 256 + threadIdx.x;
    if (i >= n4) return;
    float4 v = ((const float4*)s)[i];
    u16* o = d + i * 4;
    o[0] = f2bf(v.x); o[1] = f2bf(v.y); o[2] = f2bf(v.z); o[3] = f2bf(v.w);
}

// h_cache rows 1920..2047 per batch -> (4,128,1024) bf16
__global__ __launch_bounds__(256) void cast_win(const float* __restrict__ hc,
                                                u16* __restrict__ d)
{
    int i = blockIdx.x * 256 + threadIdx.x;
    int flat = i * 4;
    int b = flat >> 17, r = (flat >> 10) & 127, c = flat & 1023;
    float4 v = *(const float4*)(hc + ((long)b * 2048 + 1920 + r) * 1024 + c);
    u16* o = d + (long)flat;
    o[0] = f2bf(v.x); o[1] = f2bf(v.y); o[2] = f2bf(v.z); o[3] = f2bf(v.w);
}

// W (1024x1024 f32, [k][n]) -> WT (bf16 [n][k]).  grid=(32,32), block 256.
__global__ __launch_bounds__(256) void cast_transpose(const float* __restrict__ W,
                                                      u16* __restrict__ WT)
{
    __shared__ float t[32][33];
    const int bx = blockIdx.x, by = blockIdx.y;
    const int tx = threadIdx.x & 31, ty = threadIdx.x >> 5;
    #pragma unroll
    for (int p = 0; p < 4; ++p) {
        int k = by * 32 + ty + p * 8;
        t[ty + p * 8][tx] = W[(long)k * 1024 + bx * 32 + tx];
    }
    __syncthreads();
    #pragma unroll
    for (int p = 0; p < 4; ++p) {
        int n = ty + p * 8;
        WT[((long)(bx * 32 + n)) * 1024 + by * 32 + tx] = f2bf(t[tx][n]);
    }
}

// ---------------------------------------------------------------------------
// GEMM (m97-style): C = A(bf16 MxK) @ Bt^T (Bt bf16 NxK) * scale + bias.
// Tile 128x128, BK=32, 4 waves, each wave 64x64 (4x4 16x16x32 MFMA tiles).
// Staging: global_load_lds 16B/lane, contiguous LDS [row][32k] (64B rows).
// grid=(M/128, N/128, nbatch).
// ---------------------------------------------------------------------------
__global__ __launch_bounds__(256) void gemm_bt(
    const u16* __restrict__ A, long a_bstride,
    const u16* __restrict__ Bt,
    float* __restrict__ Cf, u16* __restrict__ Cb, long c_bstride,
    int N, int K, const float* __restrict__ bias, float scale)
{
    const int tid = threadIdx.x;
    const int bm = blockIdx.x, bn = blockIdx.y, bz = blockIdx.z;
    A += (long)bz * a_bstride;
    const long coff = (long)bz * c_bstride;

    __shared__ __align__(16) u16 As[128 * 32];
    __shared__ __align__(16) u16 Bs[128 * 32];

    const int lane = tid & 63, wv = tid >> 6;
    const int l15 = lane & 15, quad = lane >> 4;
    const int wm = (wv & 1) * 64, wn = (wv >> 1) * 64;

    f32x4 acc[4][4];
    #pragma unroll
    for (int i = 0; i < 4; ++i)
        #pragma unroll
        for (int j = 0; j < 4; ++j) acc[i][j] = (f32x4){0.f, 0.f, 0.f, 0.f};

    // wave wv stages rows [wv*32, wv*32+32) of both tiles, 2 chunks of 16 rows.
    const int srow = wv * 32 + (lane >> 2);
    const int scol = (lane & 3) * 8;
    const u16* a_src  = A  + (long)(bm * 128 + srow) * K + scol;
    const u16* a_src2 = a_src + (long)16 * K;
    const u16* b_src  = Bt + (long)(bn * 128 + srow) * K + scol;
    const u16* b_src2 = b_src + (long)16 * K;
    u16* lA0 = &As[(wv * 32) * 32];
    u16* lA1 = &As[(wv * 32 + 16) * 32];
    u16* lB0 = &Bs[(wv * 32) * 32];
    u16* lB1 = &Bs[(wv * 32 + 16) * 32];

    for (int k0 = 0; k0 < K; k0 += 32) {
        async16(a_src, lA0); async16(a_src2, lA1);
        async16(b_src, lB0); async16(b_src2, lB1);
        a_src += 32; a_src2 += 32; b_src += 32; b_src2 += 32;
        __syncthreads();
        short8 af[4], bfr[4];
        #pragma unroll
        for (int i = 0; i < 4; ++i)
            af[i] = *(const short8*)&As[(wm + i * 16 + l15) * 32 + quad * 8];
        #pragma unroll
        for (int j = 0; j < 4; ++j)
            bfr[j] = *(const short8*)&Bs[(wn + j * 16 + l15) * 32 + quad * 8];
        #pragma unroll
        for (int i = 0; i < 4; ++i)
            #pragma unroll
            for (int j = 0; j < 4; ++j)
                acc[i][j] = __builtin_amdgcn_mfma_f32_16x16x32_bf16(af[i], bfr[j], acc[i][j], 0, 0, 0);
        __syncthreads();
    }

    #pragma unroll
    for (int i = 0; i < 4; ++i) {
        #pragma unroll
        for (int j = 0; j < 4; ++j) {
            int col = bn * 128 + wn + j * 16 + l15;
            float bsv = bias ? bias[col] : 0.f;
            #pragma unroll
            for (int r = 0; r < 4; ++r) {
                int row = bm * 128 + wm + i * 16 + quad * 4 + r;
                float v = acc[i][j][r] * scale + bsv;
                long idx = coff + (long)row * N + col;
                if (Cf) Cf[idx] = v;
                if (Cb) Cb[idx] = f2bf(v);
            }
        }
    }
}

// ---------------------------------------------------------------------------
// Per-chunk head scores (+softmax over 32 rows) and optional compress of src.
// grid=(64, B), block 256.
// ---------------------------------------------------------------------------
__global__ __launch_bounds__(256) void scores_compress(
    const float* __restrict__ src, long src_bstride,
    const float* __restrict__ Wd, const float* __restrict__ bd,
    u16* __restrict__ out_comp, long comp_bstride,
    float* __restrict__ out_sc, long sc_bstride)
{
    const int c = blockIdx.x, b = blockIdx.y;
    const int tid = threadIdx.x;

    __shared__ __align__(16) u16 srcs[32][1032];
    __shared__ float s_sm[32][16];

    const float* sb = src + (long)b * src_bstride + (long)c * 32 * 1024;
    for (int e = tid; e < 8192; e += 256) {
        int flat = e * 4;
        int row = flat >> 10, col = flat & 1023;
        float4 v = *(const float4*)(sb + (long)row * 1024 + col);
        u16* dp = &srcs[row][col];
        dp[0] = f2bf(v.x); dp[1] = f2bf(v.y); dp[2] = f2bf(v.z); dp[3] = f2bf(v.w);
    }
    __syncthreads();

    {
        int i = tid >> 3;
        int hd0 = (tid & 7) * 2;
        float acc0 = bd[hd0], acc1 = bd[hd0 + 1];
        for (int d = 0; d < 1024; ++d) {
            float xv = bf2f(srcs[i][d]);
            float2 wp = *(const float2*)(Wd + d * 16 + hd0);
            acc0 += xv * wp.x;
            acc1 += xv * wp.y;
        }
        s_sm[i][hd0] = acc0;
        s_sm[i][hd0 + 1] = acc1;
    }
    __syncthreads();

    if (tid < 16) {
        int hd = tid;
        float m = NEGINF;
        for (int i = 0; i < 32; ++i) m = fmaxf(m, s_sm[i][hd]);
        float s = 0.f;
        for (int i = 0; i < 32; ++i) s += __expf(s_sm[i][hd] - m);
        float inv = 1.f / s;
        for (int i = 0; i < 32; ++i) s_sm[i][hd] = __expf(s_sm[i][hd] - m) * inv;
    }
    __syncthreads();

    if (out_sc) {
        for (int idx = tid; idx < 512; idx += 256) {
            int hd = idx >> 5, i = idx & 31;
            out_sc[(long)b * sc_bstride + ((long)hd * 64 + c) * 32 + i] = s_sm[i][hd];
        }
    }
    if (out_comp) {
        #pragma unroll
        for (int p = 0; p < 4; ++p) {
            int j = tid + p * 256;
            int hd = j >> 6;
            float acc = 0.f;
            for (int i = 0; i < 32; ++i) acc += s_sm[i][hd] * bf2f(srcs[i][j]);
            out_comp[(long)b * comp_bstride + (long)c * 1024 + j] = f2bf(acc);
        }
    }
}

// ---------------------------------------------------------------------------
// Compress projected k_bp/v_bp with block scores, LN -> k_comp rows 64..127
// (bf16) and vcT cols 64..127 (bf16 transposed (B,1024,128)). grid=(64,B).
// ---------------------------------------------------------------------------
__global__ __launch_bounds__(256) void compress_kv_ln(
    const float* __restrict__ kbp, const float* __restrict__ vbp,
    const float* __restrict__ sc,
    const float* __restrict__ g, const float* __restrict__ be,
    u16* __restrict__ k_comp, u16* __restrict__ vcT)
{
    const int c = blockIdx.x, b = blockIdx.y;
    const int tid = threadIdx.x;
    const int lane = tid & 63, wv = tid >> 6;

    __shared__ float scw[16][32];
    __shared__ float red[4][4];

    for (int idx = tid; idx < 512; idx += 256) {
        int hd = idx >> 5, i = idx & 31;
        scw[hd][i] = sc[((long)(b * 16 + hd) * 64 + c) * 32 + i];
    }
    __syncthreads();

    float xk[4], xv[4];
    #pragma unroll
    for (int p = 0; p < 4; ++p) {
        int j = tid + p * 256;
        int hd = j >> 6;
        float ak = 0.f, av = 0.f;
        for (int i = 0; i < 32; ++i) {
            float w = scw[hd][i];
            long off = ((long)b * 2048 + c * 32 + i) * 1024 + j;
            ak += w * kbp[off];
            av += w * vbp[off];
        }
        xk[p] = ak; xv[p] = av;
    }
    float sk = 0.f, qk = 0.f, sv = 0.f, qv = 0.f;
    #pragma unroll
    for (int p = 0; p < 4; ++p) { sk += xk[p]; qk += xk[p]*xk[p]; sv += xv[p]; qv += xv[p]*xv[p]; }
    for (int off = 32; off; off >>= 1) {
        sk += __shfl_xor(sk, off); qk += __shfl_xor(qk, off);
        sv += __shfl_xor(sv, off); qv += __shfl_xor(qv, off);
    }
    if (lane == 0) { red[0][wv] = sk; red[1][wv] = qk; red[2][wv] = sv; red[3][wv] = qv; }
    __syncthreads();
    sk = red[0][0] + red[0][1] + red[0][2] + red[0][3];
    qk = red[1][0] + red[1][1] + red[1][2] + red[1][3];
    sv = red[2][0] + red[2][1] + red[2][2] + red[2][3];
    qv = red[3][0] + red[3][1] + red[3][2] + red[3][3];
    const float inv_n = 1.f / 1024.f;
    float mk = sk * inv_n, mv = sv * inv_n;
    float ik = rsqrtf(fmaxf(qk * inv_n - mk * mk, 0.f) + 1e-5f);
    float iv = rsqrtf(fmaxf(qv * inv_n - mv * mv, 0.f) + 1e-5f);
    #pragma unroll
    for (int p = 0; p < 4; ++p) {
        int j = tid + p * 256;
        k_comp[((long)b * 128 + 64 + c) * 1024 + j] = f2bf((xk[p] - mk) * ik * g[j] + be[j]);
        vcT[((long)b * 1024 + j) * 128 + 64 + c]   = f2bf((xv[p] - mv) * iv * g[j] + be[j]);
    }
}

// ---------------------------------------------------------------------------
// Row LN (D=1024) -> bf16 normal and/or bf16 transposed. grid.x=B*rows.
// ---------------------------------------------------------------------------
__global__ __launch_bounds__(256) void ln_rows(
    const float* __restrict__ src, long src_bstride,
    u16* __restrict__ dstN, long dstN_bstride, long dstN_rowoff,
    u16* __restrict__ dstT, long dstT_coloff,
    int rows_per_batch,
    const float* __restrict__ g, const float* __restrict__ be)
{
    const int gr = blockIdx.x;
    const int b = gr / rows_per_batch, r = gr % rows_per_batch;
    const float* s = src + (long)b * src_bstride + (long)r * 1024;
    const int tid = threadIdx.x;
    const int lane = tid & 63, wv = tid >> 6;

    __shared__ float red[2][4];
    float x[4];
    float sm = 0.f, sq = 0.f;
    #pragma unroll
    for (int p = 0; p < 4; ++p) {
        x[p] = s[tid + p * 256];
        sm += x[p]; sq += x[p] * x[p];
    }
    for (int off = 32; off; off >>= 1) { sm += __shfl_xor(sm, off); sq += __shfl_xor(sq, off); }
    if (lane == 0) { red[0][wv] = sm; red[1][wv] = sq; }
    __syncthreads();
    sm = red[0][0] + red[0][1] + red[0][2] + red[0][3];
    sq = red[1][0] + red[1][1] + red[1][2] + red[1][3];
    float m = sm * (1.f / 1024.f);
    float inv = rsqrtf(fmaxf(sq * (1.f / 1024.f) - m * m, 0.f) + 1e-5f);
    #pragma unroll
    for (int p = 0; p < 4; ++p) {
        int j = tid + p * 256;
        u16 o = f2bf((x[p] - m) * inv * g[j] + be[j]);
        if (dstN) dstN[(long)b * dstN_bstride + (dstN_rowoff + r) * 1024 + j] = o;
        if (dstT) dstT[((long)b * 1024 + j) * 128 + dstT_coloff + r] = o;
    }
}

// ---------------------------------------------------------------------------
// Per-row mean/rstd (D=1024). grid.x = B*rows, block 256.
// ---------------------------------------------------------------------------
__global__ __launch_bounds__(256) void row_stats(
    const float* __restrict__ src, long src_bstride,
    float2* __restrict__ dst, long dst_bstride, long dst_row_off,
    int rows_per_batch)
{
    const int gr = blockIdx.x;
    const int b = gr / rows_per_batch, r = gr % rows_per_batch;
    const float* s = src + (long)b * src_bstride + (long)r * 1024;
    const int tid = threadIdx.x;
    const int lane = tid & 63, wv = tid >> 6;

    __shared__ float red[2][4];
    float sm = 0.f, sq = 0.f;
    #pragma unroll
    for (int p = 0; p < 4; ++p) {
        float x = s[tid + p * 256];
        sm += x; sq += x * x;
    }
    for (int off = 32; off; off >>= 1) { sm += __shfl_xor(sm, off); sq += __shfl_xor(sq, off); }
    if (lane == 0) { red[0][wv] = sm; red[1][wv] = sq; }
    __syncthreads();
    if (tid == 0) {
        sm = red[0][0] + red[0][1] + red[0][2] + red[0][3];
        sq = red[1][0] + red[1][1] + red[1][2] + red[1][3];
        float m = sm * (1.f / 1024.f);
        float inv = rsqrtf(fmaxf(sq * (1.f / 1024.f) - m * m, 0.f) + 1e-5f);
        dst[(long)b * dst_bstride + dst_row_off + r] = make_float2(m, inv);
    }
}

// ---------------------------------------------------------------------------
// Materialize window K (bf16 (B,2176,1024)) and V^T (bf16 (B,1024,2176),
// col = concat_row - 1).  grid=(34, 16, B).
// ---------------------------------------------------------------------------
__global__ __launch_bounds__(256) void win_apply(
    const float* __restrict__ kcw, const float* __restrict__ vcw,
    const float* __restrict__ kbp, const float* __restrict__ vbp,
    const float2* __restrict__ st_kw, const float2* __restrict__ st_vw,
    const float* __restrict__ g_w, const float* __restrict__ b_w,
    u16* __restrict__ kwin, u16* __restrict__ vwinT)
{
    const int tt = blockIdx.x, dc = blockIdx.y, b = blockIdx.z;
    const int t0 = tt * 64, d0 = dc * 64;
    const int tid = threadIdx.x;

    __shared__ u16 vt[64][74];

    const int r = tid >> 2;
    const int dsub = (tid & 3) * 16;
    const int t = t0 + r;
    const float* ks; const float* vs;
    if (t < 128) {
        ks = kcw + ((long)b * 128 + t) * 1024;
        vs = vcw + ((long)b * 128 + t) * 1024;
    } else {
        ks = kbp + ((long)b * 2048 + t - 128) * 1024;
        vs = vbp + ((long)b * 2048 + t - 128) * 1024;
    }
    float2 sk = st_kw[(long)b * 2176 + t];
    float2 sv = st_vw[(long)b * 2176 + t];
    #pragma unroll
    for (int j = 0; j < 16; j += 4) {
        int d = d0 + dsub + j;
        float4 kv = *(const float4*)(ks + d);
        float4 vv = *(const float4*)(vs + d);
        float4 g4 = *(const float4*)(g_w + d);
        float4 b4 = *(const float4*)(b_w + d);
        u16 ko[4];
        ko[0] = f2bf((kv.x - sk.x) * sk.y * g4.x + b4.x);
        ko[1] = f2bf((kv.y - sk.x) * sk.y * g4.y + b4.y);
        ko[2] = f2bf((kv.z - sk.x) * sk.y * g4.z + b4.z);
        ko[3] = f2bf((kv.w - sk.x) * sk.y * g4.w + b4.w);
        *(uint2*)&kwin[((long)b * 2176 + t) * 1024 + d] = *(const uint2*)ko;
        vt[r][dsub + j + 0] = f2bf((vv.x - sv.x) * sv.y * g4.x + b4.x);
        vt[r][dsub + j + 1] = f2bf((vv.y - sv.x) * sv.y * g4.y + b4.y);
        vt[r][dsub + j + 2] = f2bf((vv.z - sv.x) * sv.y * g4.z + b4.z);
        vt[r][dsub + j + 3] = f2bf((vv.w - sv.x) * sv.y * g4.w + b4.w);
    }
    __syncthreads();
    #pragma unroll
    for (int pass = 0; pass < 16; ++pass) {
        int dd = (tid >> 6) + pass * 4;
        int rr = tid & 63;
        int crow = t0 + rr;
        if (crow >= 1)
            vwinT[((long)b * 1024 + d0 + dd) * 2176 + crow - 1] = vt[rr][dd];
    }
}

// ---------------------------------------------------------------------------
// Fused MFMA attention: one block per (qc, h, b), 256 thr = 4 waves.
// logits stride 257 (conflict-free); banded bf16 P tiles built once in LDS
// (aliased over the q staging buffer) and shared by all waves for PV.
// ---------------------------------------------------------------------------
__global__ __launch_bounds__(256) void attention(
    const u16* __restrict__ qb,     // (B,2048,1024) bf16, already /8
    const u16* __restrict__ kcb,    // (B,128,1024) bf16
    const u16* __restrict__ vcT,    // (B,1024,128) bf16 transposed
    const u16* __restrict__ kwb,    // (B,2176,1024) bf16
    const u16* __restrict__ vwT,    // (B,1024,2176) bf16 transposed, col=row-1
    const u16* __restrict__ pcb,    // (128,1024) bf16
    const u16* __restrict__ ptb,    // (128,1024) bf16
    const float* __restrict__ r_w,  // (16,64)
    const float* __restrict__ r_r,
    u16* __restrict__ attn_o)       // (B,2048,1024) bf16
{
    const int qc = blockIdx.x, h = blockIdx.y, b = blockIdx.z;
    const int l0 = qc * 32;
    const int tid = threadIdx.x;
    const int lane = tid & 63, wv = tid >> 6;
    const int l15 = lane & 15, quad = lane >> 4;

    __shared__ __align__(16) float L[32 * 257];     // logits, stride 257
    __shared__ __align__(16) char uni[19456];       // qa[3][32][72] | Pc[32][136]+Pw[32][168]
    __shared__ float redm[4][32], reds[4][32];

    u16 (*qa)[32][72] = (u16 (*)[32][72])uni;       // 0:q 1:q+r_w 2:q+r_r
    u16* Pc = (u16*)uni;                            // [32][136] bf16
    u16* Pw = (u16*)(uni + 8704);                   // [32][168] bf16 (banded)

    // ---- stage q ----
    for (int e = tid; e < 2048; e += 256) {
        int r = e >> 6, d = e & 63;
        u16 qv = qb[((long)(b * 2048 + l0 + r)) * 1024 + h * 64 + d];
        float qf = bf2f(qv);
        qa[0][r][d] = qv;
        qa[1][r][d] = f2bf(qf + r_w[h * 64 + d]);
        qa[2][r][d] = f2bf(qf + r_r[h * 64 + d]);
    }
    __syncthreads();

    // ---- S_c: q·k_comp + q·pos_c[64+ci-qc], tiles 2wv..2wv+1 ----
    #pragma unroll
    for (int ti = 0; ti < 2; ++ti) {
        int n0 = (wv * 2 + ti) * 16;
        int ci = n0 + l15;
        f32x4 a0 = {0.f,0.f,0.f,0.f}, a1 = {0.f,0.f,0.f,0.f};
        if (n0 < 64 + qc) {
            int p = 64 + ci - qc; if (p > 127) p = 127;
            #pragma unroll
            for (int kc = 0; kc < 2; ++kc) {
                int k0 = kc * 32;
                short8 bk = ldg8(kcb + ((long)(b * 128 + ci)) * 1024 + h * 64 + k0 + quad * 8);
                short8 bp = ldg8(pcb + (long)p * 1024 + h * 64 + k0 + quad * 8);
                short8 fa0 = *(const short8*)&qa[0][l15][k0 + quad * 8];
                short8 fa1 = *(const short8*)&qa[0][16 + l15][k0 + quad * 8];
                a0 = __builtin_amdgcn_mfma_f32_16x16x32_bf16(fa0, bk, a0, 0, 0, 0);
                a0 = __builtin_amdgcn_mfma_f32_16x16x32_bf16(fa0, bp, a0, 0, 0, 0);
                a1 = __builtin_amdgcn_mfma_f32_16x16x32_bf16(fa1, bk, a1, 0, 0, 0);
                a1 = __builtin_amdgcn_mfma_f32_16x16x32_bf16(fa1, bp, a1, 0, 0, 0);
            }
        }
        bool msk = (ci >= 64 + qc);
        #pragma unroll
        for (int r = 0; r < 4; ++r) {
            L[(quad * 4 + r) * 257 + ci]      = msk ? NEGINF : a0[r];
            L[(16 + quad * 4 + r) * 257 + ci] = msk ? NEGINF : a1[r];
        }
    }

    // ---- S2: (q+r_r)·pos_t, tiles 2wv..2wv+1 ----
    #pragma unroll
    for (int ti = 0; ti < 2; ++ti) {
        int w0 = (wv * 2 + ti) * 16;
        int w = w0 + l15;
        f32x4 a0 = {0.f,0.f,0.f,0.f}, a1 = {0.f,0.f,0.f,0.f};
        #pragma unroll
        for (int kc = 0; kc < 2; ++kc) {
            int k0 = kc * 32;
            short8 bp = ldg8(ptb + (long)w * 1024 + h * 64 + k0 + quad * 8);
            short8 fa0 = *(const short8*)&qa[2][l15][k0 + quad * 8];
            short8 fa1 = *(const short8*)&qa[2][16 + l15][k0 + quad * 8];
            a0 = __builtin_amdgcn_mfma_f32_16x16x32_bf16(fa0, bp, a0, 0, 0, 0);
            a1 = __builtin_amdgcn_mfma_f32_16x16x32_bf16(fa1, bp, a1, 0, 0, 0);
        }
        #pragma unroll
        for (int r = 0; r < 4; ++r) {
            L[(quad * 4 + r) * 257 + 128 + w]      = a0[r];
            L[(16 + quad * 4 + r) * 257 + 128 + w] = a1[r];
        }
    }

    // ---- S1: (q+r_w)·k_win[l0+1+t], t tiles wv, wv+4, wv+8 (<10); regs ----
    f32x4 s1a[3], s1b[3];
    int nts[3]; int nw = 0;
    for (int nt = wv; nt < 10; nt += 4) {
        int t = nt * 16 + l15;
        int row = l0 + 1 + t; if (row > 2175) row = 2175;
        f32x4 a0 = {0.f,0.f,0.f,0.f}, a1 = {0.f,0.f,0.f,0.f};
        #pragma unroll
        for (int kc = 0; kc < 2; ++kc) {
            int k0 = kc * 32;
            short8 bk = ldg8(kwb + ((long)(b * 2176 + row)) * 1024 + h * 64 + k0 + quad * 8);
            short8 fa0 = *(const short8*)&qa[1][l15][k0 + quad * 8];
            short8 fa1 = *(const short8*)&qa[1][16 + l15][k0 + quad * 8];
            a0 = __builtin_amdgcn_mfma_f32_16x16x32_bf16(fa0, bk, a0, 0, 0, 0);
            a1 = __builtin_amdgcn_mfma_f32_16x16x32_bf16(fa1, bk, a1, 0, 0, 0);
        }
        s1a[nw] = a0; s1b[nw] = a1; nts[nw] = nt; ++nw;
    }
    __syncthreads();
    // band add: L[row][128 + (t-row)] += S1
    for (int i = 0; i < nw; ++i) {
        int t = nts[i] * 16 + l15;
        #pragma unroll
        for (int r = 0; r < 4; ++r) {
            int r0 = quad * 4 + r;
            int w0 = t - r0;
            if (w0 >= 0 && w0 < 128) L[r0 * 257 + 128 + w0] += s1a[i][r];
            int r1 = 16 + quad * 4 + r;
            int w1 = t - r1;
            if (w1 >= 0 && w1 < 128) L[r1 * 257 + 128 + w1] += s1b[i][r];
        }
    }
    __syncthreads();

    // ---- softmax over 256 cols (tid = col) ----
    for (int r = 0; r < 32; ++r) {
        float v = L[r * 257 + tid];
        for (int off = 32; off; off >>= 1) v = fmaxf(v, __shfl_xor(v, off));
        if (lane == 0) redm[wv][r] = v;
    }
    __syncthreads();
    for (int r = 0; r < 32; ++r) {
        float M = fmaxf(fmaxf(redm[0][r], redm[1][r]), fmaxf(redm[2][r], redm[3][r]));
        float e = __expf(L[r * 257 + tid] - M);
        L[r * 257 + tid] = e;
        float s = e;
        for (int off = 32; off; off >>= 1) s += __shfl_xor(s, off);
        if (lane == 0) reds[wv][r] = s;
    }
    __syncthreads();
    // normalize: cols<128 -> Pc (bf16, aliases dead qa); cols>=128 stay f32
    for (int r = 0; r < 32; ++r) {
        float S = reds[0][r] + reds[1][r] + reds[2][r] + reds[3][r];
        float p = L[r * 257 + tid] / S;
        if (tid < 128) Pc[r * 136 + tid] = f2bf(p);
        else           L[r * 257 + tid] = p;
    }
    __syncthreads();
    // banded window P -> bf16 (32 rows x 160 t), zeros outside band
    for (int e = tid; e < 5120; e += 256) {
        int r = e / 160, t = e - r * 160;
        int w = t - r;
        Pw[r * 168 + t] = (w >= 0 && w < 128) ? f2bf(L[r * 257 + 128 + w]) : (u16)0;
    }
    __syncthreads();

    // ---- PV: wave wv -> d-tile wv*16 ----
    const int n0d = wv * 16;
    f32x4 o0 = {0.f,0.f,0.f,0.f}, o1 = {0.f,0.f,0.f,0.f};
    #pragma unroll
    for (int kc = 0; kc < 4; ++kc) {           // compressed, K=128
        int k0 = kc * 32;
        short8 bv = ldg8(vcT + ((long)(b * 1024 + h * 64 + n0d + l15)) * 128 + k0 + quad * 8);
        short8 av0 = *(const short8*)&Pc[l15 * 136 + k0 + quad * 8];
        short8 av1 = *(const short8*)&Pc[(16 + l15) * 136 + k0 + quad * 8];
        o0 = __builtin_amdgcn_mfma_f32_16x16x32_bf16(av0, bv, o0, 0, 0, 0);
        o1 = __builtin_amdgcn_mfma_f32_16x16x32_bf16(av1, bv, o1, 0, 0, 0);
    }
    #pragma unroll
    for (int kc = 0; kc < 5; ++kc) {           // windowed, K=160 banded
        int k0 = kc * 32;
        short8 bv = ldg8(vwT + ((long)(b * 1024 + h * 64 + n0d + l15)) * 2176 + l0 + k0 + quad * 8);
        short8 av0 = *(const short8*)&Pw[l15 * 168 + k0 + quad * 8];
        short8 av1 = *(const short8*)&Pw[(16 + l15) * 168 + k0 + quad * 8];
        o0 = __builtin_amdgcn_mfma_f32_16x16x32_bf16(av0, bv, o0, 0, 0, 0);
        o1 = __builtin_amdgcn_mfma_f32_16x16x32_bf16(av1, bv, o1, 0, 0, 0);
    }
    #pragma unroll
    for (int r = 0; r < 4; ++r) {
        int r0 = quad * 4 + r, r1 = 16 + quad * 4 + r;
        attn_o[((long)(b * 2048 + l0 + r0)) * 1024 + h * 64 + n0d + l15] = f2bf(o0[r]);
        attn_o[((long)(b * 2048 + l0 + r1)) * 1024 + h * 64 + n0d + l15] = f2bf(o1[r]);
    }
}

// ---------------------------------------------------------------------------
extern "C" void kernel_launch(void* const* d_in, const int* in_sizes, int n_in,
                              void* d_out, int out_size, void* d_ws, size_t ws_size,
                              hipStream_t stream)
{
    (void)in_sizes; (void)n_in; (void)out_size; (void)ws_size;

    const float* h       = (const float*)d_in[0];
    const float* h_cache = (const float*)d_in[1];
    const float* key_pe  = (const float*)d_in[2];
    const float* pos_w   = (const float*)d_in[3];
    const float* Wq      = (const float*)d_in[4];
    const float* Wk      = (const float*)d_in[5];
    const float* Wv      = (const float*)d_in[6];
    const float* Wo      = (const float*)d_in[7];
    const float* Wd      = (const float*)d_in[8];
    const float* bd      = (const float*)d_in[9];
    const float* Wr      = (const float*)d_in[10];
    const float* br      = (const float*)d_in[11];
    const float* Wrc     = (const float*)d_in[12];
    const float* brc     = (const float*)d_in[13];
    const float* r_r     = (const float*)d_in[14];
    const float* r_w     = (const float*)d_in[15];
    const float* g_d     = (const float*)d_in[16];
    const float* b_d     = (const float*)d_in[17];
    const float* g_w     = (const float*)d_in[18];
    const float* b_w     = (const float*)d_in[19];

    char* ws = (char*)d_ws;
    size_t off = 0;
    auto alloc = [&](size_t bytes) -> void* {
        void* p = ws + off; off += (bytes + 255) & ~(size_t)255; return p;
    };
    // bf16 casts / transposed weights (N,K)
    u16* hB    = (u16*)alloc((size_t)8192 * 1024 * 2);
    u16* hcwB  = (u16*)alloc((size_t)4 * 128 * 1024 * 2);
    u16* WqT   = (u16*)alloc((size_t)1024 * 1024 * 2);
    u16* WkT   = (u16*)alloc((size_t)1024 * 1024 * 2);
    u16* WvT   = (u16*)alloc((size_t)1024 * 1024 * 2);
    u16* WoT   = (u16*)alloc((size_t)1024 * 1024 * 2);
    u16* WrT   = (u16*)alloc((size_t)1024 * 1024 * 2);
    u16* WrcT  = (u16*)alloc((size_t)1024 * 1024 * 2);
    u16* pwB   = (u16*)alloc((size_t)128 * 1024 * 2);
    u16* kpeB  = (u16*)alloc((size_t)128 * 1024 * 2);
    // intermediates
    u16*   q_ws   = (u16*)alloc((size_t)8192 * 1024 * 2);
    float* kbp    = (float*)alloc((size_t)8192 * 1024 * 4);
    float* vbp    = (float*)alloc((size_t)8192 * 1024 * 4);
    u16*   attn_o = (u16*)alloc((size_t)8192 * 1024 * 2);
    float* kcw    = (float*)alloc((size_t)4 * 128 * 1024 * 4);
    float* vcw    = (float*)alloc((size_t)4 * 128 * 1024 * 4);
    u16*   hcm    = (u16*)alloc((size_t)4 * 64 * 1024 * 2);
    float* kc_raw = (float*)alloc((size_t)4 * 64 * 1024 * 4);
    float* vc_raw = (float*)alloc((size_t)4 * 64 * 1024 * 4);
    float* sc_blk = (float*)alloc((size_t)4 * 16 * 64 * 32 * 4);
    u16*   k_comp = (u16*)alloc((size_t)4 * 128 * 1024 * 2);
    u16*   vcT    = (u16*)alloc((size_t)4 * 1024 * 128 * 2);
    float2* st_kw = (float2*)alloc((size_t)4 * 2176 * 8);
    float2* st_vw = (float2*)alloc((size_t)4 * 2176 * 8);
    u16*   pos_tb = (u16*)alloc((size_t)128 * 1024 * 2);
    u16*   pos_cb = (u16*)alloc((size_t)128 * 1024 * 2);
    u16*   kwin   = (u16*)alloc((size_t)4 * 2176 * 1024 * 2);
    u16*   vwinT  = (u16*)alloc((size_t)4 * 1024 * 2176 * 2 + 256);

    const dim3 blk(256);

    // casts + weight transposes
    cast_f2b<<<dim3(8192), blk, 0, stream>>>(h, hB, 2097152);
    cast_win<<<dim3(512), blk, 0, stream>>>(h_cache, hcwB);
    cast_transpose<<<dim3(32,32), blk, 0, stream>>>(Wq, WqT);
    cast_transpose<<<dim3(32,32), blk, 0, stream>>>(Wk, WkT);
    cast_transpose<<<dim3(32,32), blk, 0, stream>>>(Wv, WvT);
    cast_transpose<<<dim3(32,32), blk, 0, stream>>>(Wo, WoT);
    cast_transpose<<<dim3(32,32), blk, 0, stream>>>(Wr, WrT);
    cast_transpose<<<dim3(32,32), blk, 0, stream>>>(Wrc, WrcT);
    cast_f2b<<<dim3(128), blk, 0, stream>>>(pos_w, pwB, 32768);
    cast_f2b<<<dim3(128), blk, 0, stream>>>(key_pe, kpeB, 32768);

    // projections (M=8192 flattened)
    gemm_bt<<<dim3(64,8,1), blk, 0, stream>>>(hB, 0, WqT, nullptr, q_ws, 0, 1024, 1024, nullptr, 0.125f);
    gemm_bt<<<dim3(64,8,1), blk, 0, stream>>>(hB, 0, WkT, kbp, nullptr, 0, 1024, 1024, nullptr, 1.f);
    gemm_bt<<<dim3(64,8,1), blk, 0, stream>>>(hB, 0, WvT, vbp, nullptr, 0, 1024, 1024, nullptr, 1.f);
    gemm_bt<<<dim3(1,8,4), blk, 0, stream>>>(hcwB, (long)128*1024, WkT, kcw, nullptr, (long)128*1024, 1024, 1024, nullptr, 1.f);
    gemm_bt<<<dim3(1,8,4), blk, 0, stream>>>(hcwB, (long)128*1024, WvT, vcw, nullptr, (long)128*1024, 1024, 1024, nullptr, 1.f);

    // scores + compress
    scores_compress<<<dim3(64,4), blk, 0, stream>>>(h_cache, (long)2048*1024, Wd, bd,
                                                    hcm, (long)64*1024, nullptr, 0);
    scores_compress<<<dim3(64,4), blk, 0, stream>>>(h, (long)2048*1024, Wd, bd,
                                                    nullptr, 0, sc_blk, (long)16*64*32);
    gemm_bt<<<dim3(2,8,1), blk, 0, stream>>>(hcm, 0, WkT, kc_raw, nullptr, 0, 1024, 1024, nullptr, 1.f);
    gemm_bt<<<dim3(2,8,1), blk, 0, stream>>>(hcm, 0, WvT, vc_raw, nullptr, 0, 1024, 1024, nullptr, 1.f);

    compress_kv_ln<<<dim3(64,4), blk, 0, stream>>>(kbp, vbp, sc_blk, g_d, b_d, k_comp, vcT);
    ln_rows<<<dim3(256), blk, 0, stream>>>(kc_raw, (long)64*1024, k_comp, (long)128*1024, 0, nullptr, 0, 64, g_d, b_d);
    ln_rows<<<dim3(256), blk, 0, stream>>>(vc_raw, (long)64*1024, nullptr, 0, 0, vcT, 0, 64, g_d, b_d);

    // window LN
    row_stats<<<dim3(512),  blk, 0, stream>>>(kcw, (long)128*1024,  st_kw, 2176, 0,   128);
    row_stats<<<dim3(512),  blk, 0, stream>>>(vcw, (long)128*1024,  st_vw, 2176, 0,   128);
    row_stats<<<dim3(8192), blk, 0, stream>>>(kbp, (long)2048*1024, st_kw, 2176, 128, 2048);
    row_stats<<<dim3(8192), blk, 0, stream>>>(vbp, (long)2048*1024, st_vw, 2176, 128, 2048);
    win_apply<<<dim3(34,16,4), blk, 0, stream>>>(kcw, vcw, kbp, vbp, st_kw, st_vw, g_w, b_w, kwin, vwinT);

    // positional projections
    gemm_bt<<<dim3(1,8,1), blk, 0, stream>>>(pwB,  0, WrT,  nullptr, pos_tb, 0, 1024, 1024, br,  1.f);
    gemm_bt<<<dim3(1,8,1), blk, 0, stream>>>(kpeB, 0, WrcT, nullptr, pos_cb, 0, 1024, 1024, brc, 1.f);

    // attention
    attention<<<dim3(64,16,4), blk, 0, stream>>>(q_ws, k_comp, vcT, kwin, vwinT,
                                                 pos_cb, pos_tb, r_w, r_r, attn_o);
    // output projection
    gemm_bt<<<dim3(64,8,1), blk, 0, stream>>>(attn_o, 0, WoT, (float*)d_out, nullptr, 0, 1024, 1024, nullptr, 1.f);
}